// Round 16
// baseline (914.155 us; speedup 1.0000x reference)
//
#include <hip/hip_runtime.h>
#include <math.h>

typedef unsigned short u16;
typedef __attribute__((ext_vector_type(8))) short short8;
typedef __attribute__((ext_vector_type(4))) float f32x4;

#define B_ 2
#define S_ 1024
#define H_ 2048
#define DH_ 128
#define HQ_ 16
#define HKV_ 4
#define E_ 16
#define TOPK_ 4
#define I_ 1024
#define T_ (B_*S_)
#define NQKV_ 3072
#define NSEG_ 17
#define NA_ (T_*TOPK_ + T_)   /* 10240 assignments incl. shared */
#define K3_ 6144              /* logical 3*H for bf16x2 split GEMMs */
#define K2_ 4096              /* physical (hi,lo) row stride */
#define MAXTILE 97

#define QPLANE ((long)B_*HQ_*S_*DH_)   /* 4194304 */
#define KPLANE ((long)B_*HKV_*S_*DH_)  /* 1048576 */
#define VPLANE ((long)B_*HKV_*DH_*S_)  /* 1048576 */

// ---------------- numeric helpers ----------------
__device__ __forceinline__ float bf2f(u16 u){
  union { unsigned int i; float f; } x; x.i = ((unsigned int)u) << 16; return x.f;
}
__device__ __forceinline__ u16 f2bf(float f){
  union { float f; unsigned int i; } x; x.f = f;
  unsigned int r = x.i + 0x7fffu + ((x.i >> 16) & 1u);
  return (u16)(r >> 16);
}
__device__ __forceinline__ void split_bf(float v, u16& hi, u16& lo){
  hi = f2bf(v);
  lo = f2bf(v - bf2f(hi));
}

__device__ __forceinline__ void gld_lds16(const void* g, void* l){
  __builtin_amdgcn_global_load_lds(
      (const __attribute__((address_space(1))) unsigned int*)g,
      (__attribute__((address_space(3))) unsigned int*)l, 16, 0, 0);
}

__device__ __forceinline__ f32x4 mfma_bf16(short8 a, short8 b, f32x4 c){
  return __builtin_amdgcn_mfma_f32_16x16x32_bf16(a, b, c, 0, 0, 0);
}

// ---------------- weight transpose fp32 -> bf16 [N][K] (optional hi/lo split: row = (hi,lo), 2R) ----------------
__global__ void k_transpose(const float* __restrict__ in, u16* __restrict__ out,
                            int R, int C, int rowMul, int rowOff,
                            long inBatch, long outBatch, int split3)
{
  __shared__ float tile[64][65];
  const float* inp = in + (long)blockIdx.z * inBatch;
  u16* outp = out + (long)blockIdx.z * outBatch;
  int c0 = blockIdx.x * 64, r0 = blockIdx.y * 64;
  int tid = threadIdx.x;           // 256 threads
  int qc = (tid & 15) * 4;         // col quad within tile (read)
  int rr = tid >> 4;               // 0..15
#pragma unroll
  for (int p = 0; p < 4; p++){
    int r = p*16 + rr;
    float4 v = *(const float4*)(inp + (long)(r0 + r)*C + c0 + qc);
    tile[r][qc] = v.x; tile[r][qc+1] = v.y; tile[r][qc+2] = v.z; tile[r][qc+3] = v.w;
  }
  __syncthreads();
  int rl = (tid & 15) * 4;         // row quad within tile (write)
  int cw = tid >> 4;               // 0..15
#pragma unroll
  for (int p = 0; p < 4; p++){
    int c = p*16 + cw;
    float v0 = tile[rl][c], v1 = tile[rl+1][c], v2 = tile[rl+2][c], v3 = tile[rl+3][c];
    if (split3){
      ushort4 hi, lo;
      split_bf(v0, hi.x, lo.x); split_bf(v1, hi.y, lo.y);
      split_bf(v2, hi.z, lo.z); split_bf(v3, hi.w, lo.w);
      long base = (long)((c0 + c)*rowMul + rowOff) * (2*R) + r0 + rl;
      *(ushort4*)(outp + base)     = hi;
      *(ushort4*)(outp + base + R) = lo;
    } else {
      ushort4 hi = { f2bf(v0), f2bf(v1), f2bf(v2), f2bf(v3) };
      *(ushort4*)(outp + (long)((c0 + c)*rowMul + rowOff) * R + r0 + rl) = hi;
    }
  }
}

// ---------------- RMSNorm over H=2048 ((hi,lo) A-layout out, row K2_) ----------------
__global__ void k_rmsnorm(const float* __restrict__ x, const float* __restrict__ w,
                          u16* __restrict__ out2)
{
  int t = blockIdx.x;
  const float4* r4 = (const float4*)(x + (long)t * H_);
  const float4* w4 = (const float4*)w;
  float4 a = r4[threadIdx.x], b = r4[threadIdx.x + 256];
  float ss = a.x*a.x + a.y*a.y + a.z*a.z + a.w*a.w
           + b.x*b.x + b.y*b.y + b.z*b.z + b.w*b.w;
#pragma unroll
  for (int d = 1; d < 64; d <<= 1) ss += __shfl_xor(ss, d);
  __shared__ float red[4];
  int lane = threadIdx.x & 63, wv = threadIdx.x >> 6;
  if (lane == 0) red[wv] = ss;
  __syncthreads();
  ss = red[0] + red[1] + red[2] + red[3];
  float rs = rsqrtf(ss * (1.f / 2048.f) + 1e-5f);
  float4 wa = w4[threadIdx.x], wb = w4[threadIdx.x + 256];
  float va[8] = { a.x*rs*wa.x, a.y*rs*wa.y, a.z*rs*wa.z, a.w*rs*wa.w,
                  b.x*rs*wb.x, b.y*rs*wb.y, b.z*rs*wb.z, b.w*rs*wb.w };
  int pos0 = threadIdx.x*4, pos1 = 1024 + threadIdx.x*4;
  ushort4 hi0, lo0, hi1, lo1;
  split_bf(va[0], hi0.x, lo0.x); split_bf(va[1], hi0.y, lo0.y);
  split_bf(va[2], hi0.z, lo0.z); split_bf(va[3], hi0.w, lo0.w);
  split_bf(va[4], hi1.x, lo1.x); split_bf(va[5], hi1.y, lo1.y);
  split_bf(va[6], hi1.z, lo1.z); split_bf(va[7], hi1.w, lo1.w);
  u16* row = out2 + (long)t * K2_;
  *(ushort4*)(row + pos0) = hi0;        *(ushort4*)(row + pos1) = hi1;
  *(ushort4*)(row + 2048 + pos0) = lo0; *(ushort4*)(row + 2048 + pos1) = lo1;
}

// ---------------- WO + residual + RMSNorm fused ----------------
__global__ void k_add_rmsnorm(const float* __restrict__ x, const float* __restrict__ p0,
                              const float* __restrict__ w, float* __restrict__ xa,
                              u16* __restrict__ out1, float* __restrict__ outf)
{
  int t = blockIdx.x;
  long base = (long)t * H_;
  const float4* x4 = (const float4*)(x + base);
  const float4* a4 = (const float4*)(p0 + base);
  const float4* w4 = (const float4*)w;
  int i0 = threadIdx.x, i1 = threadIdx.x + 256;
  float4 xv0 = x4[i0], xv1 = x4[i1];
  float4 av0 = a4[i0], av1 = a4[i1];
  float4 s0, s1;
  s0.x = xv0.x+av0.x; s0.y = xv0.y+av0.y; s0.z = xv0.z+av0.z; s0.w = xv0.w+av0.w;
  s1.x = xv1.x+av1.x; s1.y = xv1.y+av1.y; s1.z = xv1.z+av1.z; s1.w = xv1.w+av1.w;
  *(float4*)(xa + base + i0*4) = s0;
  *(float4*)(xa + base + i1*4) = s1;
  float ss = s0.x*s0.x + s0.y*s0.y + s0.z*s0.z + s0.w*s0.w
           + s1.x*s1.x + s1.y*s1.y + s1.z*s1.z + s1.w*s1.w;
#pragma unroll
  for (int d = 1; d < 64; d <<= 1) ss += __shfl_xor(ss, d);
  __shared__ float red[4];
  int lane = threadIdx.x & 63, wv = threadIdx.x >> 6;
  if (lane == 0) red[wv] = ss;
  __syncthreads();
  ss = red[0] + red[1] + red[2] + red[3];
  float rs = rsqrtf(ss * (1.f / 2048.f) + 1e-5f);
  float4 wa = w4[i0], wb = w4[i1];
  float va[8] = { s0.x*rs*wa.x, s0.y*rs*wa.y, s0.z*rs*wa.z, s0.w*rs*wa.w,
                  s1.x*rs*wb.x, s1.y*rs*wb.y, s1.z*rs*wb.z, s1.w*rs*wb.w };
  ushort4 q0 = { f2bf(va[0]), f2bf(va[1]), f2bf(va[2]), f2bf(va[3]) };
  ushort4 q1 = { f2bf(va[4]), f2bf(va[5]), f2bf(va[6]), f2bf(va[7]) };
  *(ushort4*)(out1 + base + i0*4) = q0;
  *(ushort4*)(out1 + base + i1*4) = q1;
  float4 oa = { va[0], va[1], va[2], va[3] };
  float4 ob = { va[4], va[5], va[6], va[7] };
  *(float4*)(outf + base + i0*4) = oa;
  *(float4*)(outf + base + i1*4) = ob;
}

// ---------------- RoPE table (fp64) ----------------
__global__ void k_ropetab(float* __restrict__ tab){
  int s = blockIdx.x, i = threadIdx.x; // 64 threads
  double inv = pow(10000.0, -(double)i / 64.0);
  double fr = (double)s * inv;
  tab[s*128 + i]      = (float)cos(fr);
  tab[s*128 + 64 + i] = (float)sin(fr);
}

// ---------------- per-head QK norm + RoPE + hi/lo split layout ----------------
__global__ void k_ropenorm(const float* __restrict__ qkv, const float* __restrict__ biascat,
                           const float* __restrict__ qnw, const float* __restrict__ knw,
                           const float* __restrict__ tab,
                           u16* __restrict__ Q, u16* __restrict__ Kn, u16* __restrict__ Vt)
{
  long gw = (long)blockIdx.x * 4 + (threadIdx.x >> 6);
  int lane = threadIdx.x & 63;
  int hr = (int)(gw % 24);
  long bs = gw / 24;            // token index t = b*S + s
  int s = (int)(bs % S_);
  int b = (int)(bs / S_);
  long ro = bs * NQKV_ + hr * DH_;
  float x1 = qkv[ro + lane] + biascat[hr*DH_ + lane];
  float x2 = qkv[ro + lane + 64] + biascat[hr*DH_ + lane + 64];
  if (hr < 20){
    float ss = x1*x1 + x2*x2;
#pragma unroll
    for (int d = 1; d < 64; d <<= 1) ss += __shfl_xor(ss, d);
    float rs = rsqrtf(ss * (1.f/128.f) + 1e-5f);
    const float* wn = (hr < 16) ? qnw : knw;
    float y1 = x1 * rs * wn[lane], y2 = x2 * rs * wn[lane + 64];
    float c = tab[s*128 + lane], sn = tab[s*128 + 64 + lane];
    float o1 = y1*c - y2*sn, o2 = y2*c + y1*sn;
    if (hr < 16){
      const float sc = 0.088388347648318447f; // 1/sqrt(128)
      u16 h1,l1,h2,l2;
      split_bf(o1*sc, h1, l1); split_bf(o2*sc, h2, l2);
      u16* dst = Q + (((long)b*HQ_ + hr)*S_ + s) * DH_;
      dst[lane] = h1; dst[lane+64] = h2;
      dst[QPLANE + lane] = l1; dst[QPLANE + lane+64] = l2;
    } else {
      u16 h1,l1,h2,l2;
      split_bf(o1, h1, l1); split_bf(o2, h2, l2);
      u16* dst = Kn + (((long)b*HKV_ + (hr-16))*S_ + s) * DH_;
      dst[lane] = h1; dst[lane+64] = h2;
      dst[KPLANE + lane] = l1; dst[KPLANE + lane+64] = l2;
    }
  } else {
    u16 h1,l1,h2,l2;
    split_bf(x1, h1, l1); split_bf(x2, h2, l2);
    u16* dst = Vt + (((long)b*HKV_ + (hr-20))*DH_) * S_ + s;
    dst[(long)lane * S_]        = h1;
    dst[(long)(lane + 64) * S_] = h2;
    dst[VPLANE + (long)lane * S_]        = l1;
    dst[VPLANE + (long)(lane + 64) * S_] = l2;
  }
}

// ---------------- flash attention (causal, GQA 4:1), bf16x2 3-term MFMA ----------------
__launch_bounds__(256)
__global__ void k_attn(const u16* __restrict__ Q, const u16* __restrict__ Kn,
                       const u16* __restrict__ Vt, u16* __restrict__ O2)
{
  __shared__ u16 LDS[2*16384];
  int qb = (gridDim.x - 1) - blockIdx.x;   // longest blocks first (LPT)
  int h = blockIdx.y, b = blockIdx.z;
  int kvh = h >> 2;
  int q0 = qb * 64;
  int tid = threadIdx.x, lane = tid & 63, w = tid >> 6;

  const u16* Qg = Q  + (((long)b*HQ_  + h  )*S_ + q0) * DH_;
  const u16* Kg = Kn + (((long)b*HKV_ + kvh)*S_) * DH_;
  const u16* Vg = Vt + (((long)b*HKV_ + kvh)*DH_) * S_;

  short8 qh[4], ql[4];
  {
    long qrow = w*16 + (lane & 15);
    int coff = (lane >> 4) << 3;
#pragma unroll
    for (int kst = 0; kst < 4; kst++){
      qh[kst] = *(const short8*)(Qg + qrow*DH_ + kst*32 + coff);
      ql[kst] = *(const short8*)(Qg + QPLANE + qrow*DH_ + kst*32 + coff);
    }
  }

  long ksrc[2]; int kdst[2];
  long vsrc[2]; int vdst[2];
#pragma unroll
  for (int it = 0; it < 2; ++it){
    {
      int flat = it*256 + tid;
      int r = flat >> 4, pc = flat & 15;
      int c = pc ^ (((r&7) << 1) | ((r >> 3) & 1));
      ksrc[it] = (long)r*DH_ + c*8;
      kdst[it] = (it*256 + (w<<6))*8;
    }
    {
      int flat = it*256 + tid;
      int r = flat >> 2, pc = flat & 3;
      int c = pc ^ (r & 3);
      vsrc[it] = (long)r*S_ + c*8;
      vdst[it] = 8192 + (it*256 + (w<<6))*8;
    }
  }

  auto STAGE_K = [&](int jj){
    int bo = (jj & 1) * 16384;
    long joff = (long)jj*32*DH_;
#pragma unroll
    for (int it = 0; it < 2; ++it){
      gld_lds16(Kg + ksrc[it] + joff,          &LDS[bo + kdst[it]]);
      gld_lds16(Kg + KPLANE + ksrc[it] + joff, &LDS[bo + 4096 + kdst[it]]);
    }
  };
  auto STAGE_V = [&](int jj){
    int bo = (jj & 1) * 16384;
    long joff = (long)jj*32;
#pragma unroll
    for (int it = 0; it < 2; ++it){
      gld_lds16(Vg + vsrc[it] + joff,          &LDS[bo + vdst[it]]);
      gld_lds16(Vg + VPLANE + vsrc[it] + joff, &LDS[bo + 4096 + vdst[it]]);
    }
  };

  f32x4 o[8];
#pragma unroll
  for (int nt = 0; nt < 8; nt++) o[nt] = (f32x4){0.f,0.f,0.f,0.f};
  float mrow[4] = {-INFINITY,-INFINITY,-INFINITY,-INFINITY};
  float lrow[4] = {0.f,0.f,0.f,0.f};

  int jmax = 2*qb + 1;
  STAGE_K(0);
  STAGE_V(0);

  for (int j = 0; j <= jmax; ++j){
    if (j < jmax){
      STAGE_K(j+1);
      asm volatile("s_waitcnt vmcnt(8)" ::: "memory");
    } else {
      asm volatile("s_waitcnt vmcnt(4)" ::: "memory");
    }
    __builtin_amdgcn_s_barrier();
    __builtin_amdgcn_sched_barrier(0);

    const u16* Lb = &LDS[(j & 1) * 16384];
    u16* Pb = &LDS[((j + 1) & 1) * 16384 + 8192];

    f32x4 s[2];
#pragma unroll
    for (int nt = 0; nt < 2; nt++) s[nt] = (f32x4){0.f,0.f,0.f,0.f};
#pragma unroll
    for (int kst = 0; kst < 4; kst++){
#pragma unroll
      for (int nt = 0; nt < 2; nt++){
        int br = nt*16 + (lane & 15);
        int bc = (kst*4 + (lane >> 4)) ^ (((br&7)<<1) | ((br>>3)&1));
        short8 kh = *(const short8*)(Lb + br*128 + bc*8);
        short8 kl = *(const short8*)(Lb + 4096 + br*128 + bc*8);
        s[nt] = mfma_bf16(qh[kst], kh, s[nt]);
        s[nt] = mfma_bf16(qh[kst], kl, s[nt]);
        s[nt] = mfma_bf16(ql[kst], kh, s[nt]);
      }
    }
    if (j >= 2*qb){
#pragma unroll
      for (int nt = 0; nt < 2; nt++){
        int key = j*32 + nt*16 + (lane & 15);
#pragma unroll
        for (int r = 0; r < 4; r++){
          int qrow = q0 + w*16 + ((lane >> 4) << 2) + r;
          if (key > qrow) s[nt][r] = -1e30f;
        }
      }
    }
    float pm[4];
#pragma unroll
    for (int r = 0; r < 4; r++) pm[r] = fmaxf(s[0][r], s[1][r]);
#pragma unroll
    for (int d = 1; d < 16; d <<= 1){
#pragma unroll
      for (int r = 0; r < 4; r++) pm[r] = fmaxf(pm[r], __shfl_xor(pm[r], d));
    }
    float alpha[4];
#pragma unroll
    for (int r = 0; r < 4; r++){
      float mn = fmaxf(mrow[r], pm[r]);
      alpha[r] = __expf(mrow[r] - mn);
      mrow[r] = mn;
    }
    float psum[4] = {0.f,0.f,0.f,0.f};
#pragma unroll
    for (int nt = 0; nt < 2; nt++){
#pragma unroll
      for (int r = 0; r < 4; r++){
        float p = __expf(s[nt][r] - mrow[r]);
        psum[r] += p;
        u16 ph, pl; split_bf(p, ph, pl);
        int qr = ((lane>>4)<<2) + r, kc = nt*16 + (lane & 15);
        Pb[w*640 + qr*40 + kc]        = ph;
        Pb[2560 + w*640 + qr*40 + kc] = pl;
      }
    }
#pragma unroll
    for (int d = 1; d < 16; d <<= 1){
#pragma unroll
      for (int r = 0; r < 4; r++) psum[r] += __shfl_xor(psum[r], d);
    }
#pragma unroll
    for (int r = 0; r < 4; r++) lrow[r] = lrow[r]*alpha[r] + psum[r];
#pragma unroll
    for (int nt = 0; nt < 8; nt++)
#pragma unroll
      for (int r = 0; r < 4; r++) o[nt][r] *= alpha[r];

    if (j < jmax) asm volatile("s_waitcnt vmcnt(4)" ::: "memory");
    else          asm volatile("s_waitcnt vmcnt(0)" ::: "memory");
    __builtin_amdgcn_s_barrier();
    __builtin_amdgcn_sched_barrier(0);

    {
      short8 pah = *(const short8*)(Pb + w*640 + (lane & 15)*40 + ((lane >> 4) << 3));
      short8 pal = *(const short8*)(Pb + 2560 + w*640 + (lane & 15)*40 + ((lane >> 4) << 3));
#pragma unroll
      for (int nt = 0; nt < 8; nt++){
        int br = nt*16 + (lane & 15);
        int bc = (lane >> 4) ^ (br & 3);
        short8 vh = *(const short8*)(Lb + 8192 + br*32 + bc*8);
        short8 vl = *(const short8*)(Lb + 12288 + br*32 + bc*8);
        o[nt] = mfma_bf16(pah, vh, o[nt]);
        o[nt] = mfma_bf16(pah, vl, o[nt]);
        o[nt] = mfma_bf16(pal, vh, o[nt]);
      }
    }
    asm volatile("s_waitcnt lgkmcnt(0)" ::: "memory");
    __builtin_amdgcn_sched_barrier(0);
    __builtin_amdgcn_s_barrier();
    if (j < jmax) STAGE_V(j+1);
  }

  float inv_[4];
#pragma unroll
  for (int r = 0; r < 4; r++) inv_[r] = 1.f / lrow[r];
#pragma unroll
  for (int nt = 0; nt < 8; nt++){
#pragma unroll
    for (int r = 0; r < 4; r++){
      long row = (long)b*S_ + q0 + w*16 + ((lane >> 4) << 2) + r;
      float val = o[nt][r] * inv_[r];
      u16 hi, lo; split_bf(val, hi, lo);
      long base = row*K2_ + h*DH_ + nt*16 + (lane & 15);
      O2[base]        = hi;
      O2[base + 2048] = lo;
    }
  }
}

// ---------------- dense pipelined 128x128 GEMM (BK=32, 4-deep LDS, counted vmcnt) ----------------
template<int KITERS>
__launch_bounds__(256)
__global__ void k_gemm_d(const u16* __restrict__ A, const u16* __restrict__ Bm,
                         float* __restrict__ C, int N)
{
  __shared__ u16 LDS[4*8192];
  int tid = threadIdx.x;
  int lane = tid & 63, w = tid >> 6;
  int wr = w >> 1, wc = w & 1;
  int n0 = blockIdx.x * 128;
  int m0 = blockIdx.y * 128;

  const u16* aS[2]; const u16* bS[2];
#pragma unroll
  for (int it = 0; it < 2; ++it){
    int c = w + it*4;
    int row = c*16 + (lane >> 2);
    int ps = (lane & 3) ^ ((row >> 1) & 3);
    aS[it] = A + (long)(m0 + row) * K2_ + ps*8;
    bS[it] = Bm + (long)(n0 + row) * K2_ + ps*8;
  }

  int offA[4], offB[4];
#pragma unroll
  for (int m = 0; m < 4; m++){
    int r = wr*64 + m*16 + (lane & 15);
    int ps = (lane >> 4) ^ ((r >> 1) & 3);
    offA[m] = r*32 + ps*8;
  }
#pragma unroll
  for (int n = 0; n < 4; n++){
    int r = wc*64 + n*16 + (lane & 15);
    int ps = (lane >> 4) ^ ((r >> 1) & 3);
    offB[n] = 4096 + r*32 + ps*8;
  }

  f32x4 acc[4][4];
#pragma unroll
  for (int m = 0; m < 4; m++)
#pragma unroll
    for (int n = 0; n < 4; n++) acc[m][n] = (f32x4){0.f,0.f,0.f,0.f};

  auto STAGE = [&](int Tt){
    int kb = Tt * 32;
    int kA = (kb < 2048) ? kb : kb - 2048;
    int kB = (kb < 4096) ? kb : kb - 4096;
    int db = (Tt & 3) * 8192;
#pragma unroll
    for (int it = 0; it < 2; ++it){
      gld_lds16(aS[it] + kA, &LDS[db + (w + it*4)*512]);
      gld_lds16(bS[it] + kB, &LDS[db + 4096 + (w + it*4)*512]);
    }
  };

  STAGE(0); STAGE(1); STAGE(2);

  for (int T = 0; T < KITERS; ++T){
    if (T + 3 < KITERS) STAGE(T + 3);
    int rem = KITERS - 1 - T;
    if (rem >= 3)      asm volatile("s_waitcnt vmcnt(12)" ::: "memory");
    else if (rem == 2) asm volatile("s_waitcnt vmcnt(8)"  ::: "memory");
    else if (rem == 1) asm volatile("s_waitcnt vmcnt(4)"  ::: "memory");
    else               asm volatile("s_waitcnt vmcnt(0)"  ::: "memory");
    __builtin_amdgcn_s_barrier();
    __builtin_amdgcn_sched_barrier(0);
    const u16* L = &LDS[(T & 3) * 8192];
    short8 af[4], bfv[4];
#pragma unroll
    for (int m = 0; m < 4; m++) af[m]  = *(const short8*)(L + offA[m]);
#pragma unroll
    for (int n = 0; n < 4; n++) bfv[n] = *(const short8*)(L + offB[n]);
#pragma unroll
    for (int m = 0; m < 4; m++)
#pragma unroll
      for (int n = 0; n < 4; n++)
        acc[m][n] = mfma_bf16(af[m], bfv[n], acc[m][n]);
    asm volatile("s_waitcnt lgkmcnt(0)" ::: "memory");
    __builtin_amdgcn_sched_barrier(0);
    __builtin_amdgcn_s_barrier();
  }

#pragma unroll
  for (int m = 0; m < 4; m++){
    int row0 = m0 + wr*64 + m*16 + ((lane >> 4) << 2);
#pragma unroll
    for (int n = 0; n < 4; n++){
      int col = n0 + wc*64 + n*16 + (lane & 15);
#pragma unroll
      for (int r = 0; r < 4; r++)
        C[(long)(row0 + r)*N + col] = acc[m][n][r];
    }
  }
}

// ---------------- grouped 128x128 GEMM, BK=64, B-only double-buffer (48KB LDS) ----------------
// Grid (tiles, n-blocks) x-major: consecutive blocks = same-expert m-tiles at same n0
// -> shared 512KB B-slice L2-reuse (B stream dominates traffic).
template<int MODE>
__launch_bounds__(256)
__global__ void k_gemm_g(const u16* __restrict__ A, const u16* __restrict__ Bm,
                         void* __restrict__ Cout,
                         int Kloop, long segStrideB,
                         const int* __restrict__ segStart, const int* __restrict__ segCount,
                         const int* __restrict__ tileSeg, const int* __restrict__ tileMb,
                         const int* __restrict__ meta,
                         const int* __restrict__ assignTS, const float* __restrict__ assignW,
                         u16* __restrict__ downb)
{
  __shared__ u16 LDS[3*8192];   // A: [0,8192), B0: [8192,16384), B1: [16384,24576)
  int tid = threadIdx.x;
  int lane = tid & 63, w = tid >> 6;
  int wr = w >> 1, wc = w & 1;
  int ty = blockIdx.x;
  if (ty >= meta[0]) return;
  int n0 = blockIdx.y * 128;
  int seg = tileSeg[ty], m0 = tileMb[ty] * 128;
  int segBase = segStart[seg];
  int cnt = segCount[seg];
  const u16* Bp = Bm + (long)seg * segStrideB;

  const u16* aS[4]; const u16* bS[4];
#pragma unroll
  for (int it = 0; it < 4; ++it){
    int flat = it*256 + tid;
    int r = flat >> 3, pc = flat & 7;
    int c = pc ^ (r & 7);
    long arow;
    if constexpr (MODE == 2) arow = (long)(assignTS[segBase + m0 + r] >> 3);
    else arow = (long)(segBase + m0 + r);
    aS[it] = A + arow * Kloop + c*8;
    bS[it] = Bp + (long)(n0 + r) * Kloop + c*8;
  }

  auto STAGE_A = [&](int Tt){
    int kb = Tt * 64;
#pragma unroll
    for (int it = 0; it < 4; ++it)
      gld_lds16(aS[it] + kb, &LDS[(it*256 + (w<<6))*8]);
  };
  auto STAGE_B = [&](int Tt){
    int kb = Tt * 64;
    int bb = 8192 + (Tt & 1)*8192;
#pragma unroll
    for (int it = 0; it < 4; ++it)
      gld_lds16(bS[it] + kb, &LDS[bb + (it*256 + (w<<6))*8]);
  };

  f32x4 acc[4][4];
#pragma unroll
  for (int m = 0; m < 4; m++)
#pragma unroll
    for (int n = 0; n < 4; n++) acc[m][n] = (f32x4){0.f,0.f,0.f,0.f};

  int NT = Kloop >> 6;
  STAGE_A(0); STAGE_B(0);

  for (int T = 0; T < NT; ++T){
    if (T + 1 < NT){
      STAGE_B(T + 1);
      asm volatile("s_waitcnt vmcnt(4)" ::: "memory");   // A(T)+B(T) landed; B(T+1) in flight
    } else {
      asm volatile("s_waitcnt vmcnt(0)" ::: "memory");
    }
    __builtin_amdgcn_s_barrier();
    __builtin_amdgcn_sched_barrier(0);
    const u16* Bb = &LDS[8192 + (T & 1)*8192];
#pragma unroll
    for (int kh = 0; kh < 2; ++kh){
      short8 af[4], bfv[4];
#pragma unroll
      for (int m = 0; m < 4; m++){
        int r = wr*64 + m*16 + (lane & 15);
        int c = (kh*4 + (lane >> 4)) ^ (r & 7);
        af[m] = *(const short8*)(&LDS[0] + r*64 + c*8);
      }
#pragma unroll
      for (int n = 0; n < 4; n++){
        int r = wc*64 + n*16 + (lane & 15);
        int c = (kh*4 + (lane >> 4)) ^ (r & 7);
        bfv[n] = *(const short8*)(Bb + r*64 + c*8);
      }
#pragma unroll
      for (int m = 0; m < 4; m++)
#pragma unroll
        for (int n = 0; n < 4; n++)
          acc[m][n] = mfma_bf16(af[m], bfv[n], acc[m][n]);
    }
    asm volatile("s_waitcnt lgkmcnt(0)" ::: "memory");
    __builtin_amdgcn_sched_barrier(0);
    __builtin_amdgcn_s_barrier();
    if (T + 1 < NT) STAGE_A(T + 1);   // A-buf readers done (lgkm drained + barrier)
  }

  if constexpr (MODE == 2){
    u16* inter = (u16*)Cout;
#pragma unroll
    for (int m = 0; m < 4; m++){
      int row0 = m0 + wr*64 + m*16 + ((lane >> 4) << 2);
#pragma unroll
      for (int n = 0; n < 4; n++){
        f32x4 a = acc[m][n];
        float ov[4];
#pragma unroll
        for (int r = 0; r < 4; r++) ov[r] = __shfl_xor(a[r], 1);
        if ((lane & 1) == 0){
          int colp = (n0 + wc*64 + n*16 + (lane & 15)) >> 1;
#pragma unroll
          for (int r = 0; r < 4; r++){
            int rl = row0 + r;
            if (rl < cnt){
              int pos = segBase + rl;
              float g = a[r], u = ov[r];
              float val = (g / (1.f + __expf(-g))) * u * assignW[pos];
              inter[(long)pos*I_ + colp] = f2bf(val);
            }
          }
        }
      }
    }
  } else {
#pragma unroll
    for (int m = 0; m < 4; m++){
      int row0 = m0 + wr*64 + m*16 + ((lane >> 4) << 2);
#pragma unroll
      for (int n = 0; n < 4; n++){
        int col = n0 + wc*64 + n*16 + (lane & 15);
#pragma unroll
        for (int r = 0; r < 4; r++){
          int rl = row0 + r;
          if (rl < cnt){
            int ts = assignTS[segBase + rl];
            downb[((long)(ts >> 3)*5 + (ts & 7))*H_ + col] = f2bf(acc[m][n][r]);
          }
        }
      }
    }
  }
}

// ---------------- router (fp32, wave-per-token, streamed row / all-expert acc) ----------------
__global__ void k_router(const float* __restrict__ ht, const float* __restrict__ gw,
                         const float* __restrict__ gb, int* __restrict__ tok_e,
                         float* __restrict__ tok_w, int* __restrict__ counts)
{
  int t = blockIdx.x * 4 + (threadIdx.x >> 6);
  int lane = threadIdx.x & 63;
  const float4* row4 = (const float4*)(ht + (long)t * H_);
  float acc[16];
#pragma unroll
  for (int e = 0; e < 16; e++) acc[e] = 0.f;
#pragma unroll
  for (int it = 0; it < 8; it++){
    float4 rv = row4[lane + 64*it];
#pragma unroll
    for (int e = 0; e < 16; e++){
      float4 gv = *(const float4*)(gw + (long)e*H_ + (lane + 64*it)*4);
      acc[e] += rv.x*gv.x + rv.y*gv.y + rv.z*gv.z + rv.w*gv.w;
    }
  }
#pragma unroll
  for (int d = 1; d < 64; d <<= 1){
#pragma unroll
    for (int e = 0; e < 16; e++) acc[e] += __shfl_xor(acc[e], d);
  }
  if (lane == 0){
    float scr[16], ch[16];
#pragma unroll
    for (int e = 0; e < 16; e++){
      float s = 1.f / (1.f + __expf(-acc[e]));
      scr[e] = s; ch[e] = s + gb[e];
    }
    int sel[4]; float tw[4]; float sum = 0.f;
#pragma unroll
    for (int k = 0; k < 4; k++){
      int best = -1; float bv = -1e30f;
      for (int e = 0; e < 16; e++){
        bool used = false;
        for (int j = 0; j < k; j++) if (sel[j] == e) used = true;
        if (!used && ch[e] > bv){ bv = ch[e]; best = e; }
      }
      sel[k] = best; tw[k] = scr[best]; sum += scr[best];
    }
    float inv = 1.f / (sum + 1e-20f);
#pragma unroll
    for (int k = 0; k < 4; k++){
      tok_e[t*4 + k] = sel[k];
      tok_w[t*4 + k] = tw[k] * inv;
      atomicAdd(&counts[sel[k]], 1);
    }
  }
}

__global__ void k_scan(const int* __restrict__ counts, int* __restrict__ segStart,
                       int* __restrict__ segCount, int* __restrict__ cursor,
                       int* __restrict__ tileSeg, int* __restrict__ tileMb,
                       int* __restrict__ meta)
{
  if (threadIdx.x == 0){
    int off = 0, nt = 0;
    for (int e = 0; e < 16; e++){
      segStart[e] = off; segCount[e] = counts[e]; cursor[e] = off;
      for (int mb = 0; mb*128 < counts[e]; ++mb){ tileSeg[nt] = e; tileMb[nt] = mb; nt++; }
      off += counts[e];
    }
    segStart[16] = T_*TOPK_; segCount[16] = T_;
    for (int mb = 0; mb < 16; ++mb){ tileSeg[nt] = 16; tileMb[nt] = mb; nt++; }
    meta[0] = nt;
  }
}

__global__ void k_scatter(const int* __restrict__ tok_e, const float* __restrict__ tok_w,
                          int* __restrict__ cursor, int* __restrict__ assignTS,
                          float* __restrict__ assignW)
{
  int t = blockIdx.x*256 + threadIdx.x;
  if (t < T_){
    for (int k = 0; k < 4; k++){
      int e = tok_e[t*4 + k];
      int pos = atomicAdd(&cursor[e], 1);
      assignTS[pos] = t*8 + k;
      assignW[pos] = tok_w[t*4 + k];
    }
    assignTS[T_*TOPK_ + t] = t*8 + 4;
    assignW[T_*TOPK_ + t] = 1.f;
  }
}

// ---------------- final: out = xa + sum_slots down ----------------
__global__ void k_final(const float* __restrict__ xa, const u16* __restrict__ downb,
                        float* __restrict__ out)
{
  long i = ((long)blockIdx.x*256 + threadIdx.x) * 4;
  int t = (int)(i >> 11);
  int h = (int)(i & 2047);
  float4 r = *(const float4*)(xa + i);
  float a0 = r.x, a1 = r.y, a2 = r.z, a3 = r.w;
#pragma unroll
  for (int k = 0; k < 5; k++){
    const u16* d = downb + ((long)t*5 + k)*H_ + h;
    ushort4 v = *(const ushort4*)d;
    a0 += bf2f(v.x); a1 += bf2f(v.y); a2 += bf2f(v.z); a3 += bf2f(v.w);
  }
  float4 o = { a0, a1, a2, a3 };
  *(float4*)(out + i) = o;
}

// ---------------- host ----------------
extern "C" void kernel_launch(void* const* d_in, const int* in_sizes, int n_in,
                              void* d_out, int out_size, void* d_ws, size_t ws_size,
                              hipStream_t stream)
{
  (void)in_sizes; (void)n_in; (void)out_size; (void)ws_size;
  const float* x      = (const float*)d_in[0];
  const float* inlnw  = (const float*)d_in[1];
  const float* wq     = (const float*)d_in[2];
  const float* bq     = (const float*)d_in[3];
  const float* wk     = (const float*)d_in[4];
  const float* bk     = (const float*)d_in[5];
  const float* wv     = (const float*)d_in[6];
  const float* bv     = (const float*)d_in[7];
  const float* qnw    = (const float*)d_in[8];
  const float* knw    = (const float*)d_in[9];
  const float* wo     = (const float*)d_in[10];
  const float* postln = (const float*)d_in[11];
  const float* gatew  = (const float*)d_in[12];
  const float* gateb  = (const float*)d_in[13];
  const float* wg     = (const float*)d_in[14];
  const float* wu     = (const float*)d_in[15];
  const float* wdp    = (const float*)d_in[16];
  const float* swg    = (const float*)d_in[17];
  const float* swu    = (const float*)d_in[18];
  const float* swd    = (const float*)d_in[19];
  float* out = (float*)d_out;

  char* ws = (char*)d_ws;
  size_t off = 0;
  auto alloc = [&](size_t bytes) -> char* {
    char* p = ws + off; off += (bytes + 255) & ~(size_t)255; return p;
  };
  // persistent
  u16*   wqkv2   = (u16*)  alloc((size_t)NQKV_*K2_*2);     // 25.17 MB (hi,lo)
  u16*   wo2     = (u16*)  alloc((size_t)H_*K2_*2);        // 16.78 MB (hi,lo)
  u16*   wgu_t   = (u16*)  alloc((size_t)NSEG_*2048*2048*2); // 142.6 MB
  u16*   wd_t    = (u16*)  alloc((size_t)NSEG_*2048*1024*2); // 71.3 MB
  float* tab     = (float*)alloc((size_t)S_*128*4);
  float* biascat = (float*)alloc((size_t)NQKV_*4);
  float* xa      = (float*)alloc((size_t)T_*H_*4);         // 16.78 MB
  int*   tok_e   = (int*)  alloc((size_t)T_*4*4);
  float* tok_w   = (float*)alloc((size_t)T_*4*4);
  int*   counts  = (int*)  alloc(32*4);
  int*   segStart= (int*)  alloc(32*4);
  int*   segCount= (int*)  alloc(32*4);
  int*   cursor  = (int*)  alloc(32*4);
  int*   tileSeg = (int*)  alloc(128*4);
  int*   tileMb  = (int*)  alloc(128*4);
  int*   meta    = (int*)  alloc(32*4);
  int*   assignTS= (int*)  alloc((size_t)NA_*4);
  float* assignW = (float*)alloc((size_t)NA_*4);
  // scratch regions (re-used across phases)
  char*  scrA    = alloc((size_t)NA_*I_*2);                // 20.97 MB: h2 -> attno2 -> inter
  char*  scrBC   = alloc((size_t)2*T_*NQKV_*4);            // 50.33 MB: qkv -> wop
  char*  scrD    = alloc((size_t)(2*QPLANE + 2*KPLANE + 2*VPLANE)*2); // 25.17 MB: Q/K/V -> ht -> downb

  u16*   h2      = (u16*)scrA;
  u16*   attno2  = (u16*)scrA;
  u16*   inter   = (u16*)scrA;
  float* qkvp0   = (float*)scrBC;
  float* wop     = (float*)scrBC;
  u16*   Qb2     = (u16*)scrD;
  u16*   Kn2     = (u16*)(scrD + (size_t)2*QPLANE*2);
  u16*   Vt2     = (u16*)(scrD + (size_t)2*QPLANE*2 + (size_t)2*KPLANE*2);
  float* ht_f    = (float*)scrD;
  u16*   ht_b    = (u16*)(scrD + (size_t)T_*H_*4);
  u16*   downb   = (u16*)scrD;

  // weight conversion (64x64 tiles, 256 threads); split weights (hi,lo) 2R rows
  k_transpose<<<dim3(32,32,1),  256, 0, stream>>>(wq,  wqkv2, 2048, 2048, 1, 0,    0, 0, 1);
  k_transpose<<<dim3(8,32,1),   256, 0, stream>>>(wk,  wqkv2, 2048, 512,  1, 2048, 0, 0, 1);
  k_transpose<<<dim3(8,32,1),   256, 0, stream>>>(wv,  wqkv2, 2048, 512,  1, 2560, 0, 0, 1);
  k_transpose<<<dim3(32,32,1),  256, 0, stream>>>(wo,  wo2,   2048, 2048, 1, 0,    0, 0, 1);
  k_transpose<<<dim3(16,32,16), 256, 0, stream>>>(wg,  wgu_t, 2048, 1024, 2, 0, (long)2048*1024, (long)2048*2048, 0);
  k_transpose<<<dim3(16,32,16), 256, 0, stream>>>(wu,  wgu_t, 2048, 1024, 2, 1, (long)2048*1024, (long)2048*2048, 0);
  k_transpose<<<dim3(16,32,1),  256, 0, stream>>>(swg, wgu_t + (long)16*2048*2048, 2048, 1024, 2, 0, 0, 0, 0);
  k_transpose<<<dim3(16,32,1),  256, 0, stream>>>(swu, wgu_t + (long)16*2048*2048, 2048, 1024, 2, 1, 0, 0, 0);
  k_transpose<<<dim3(32,16,16), 256, 0, stream>>>(wdp, wd_t,  1024, 2048, 1, 0, (long)1024*2048, (long)2048*1024, 0);
  k_transpose<<<dim3(32,16,1),  256, 0, stream>>>(swd, wd_t + (long)16*2048*1024, 1024, 2048, 1, 0, 0, 0, 0);

  hipMemcpyAsync(biascat,        bq, 2048*4, hipMemcpyDeviceToDevice, stream);
  hipMemcpyAsync(biascat + 2048, bk, 512*4,  hipMemcpyDeviceToDevice, stream);
  hipMemcpyAsync(biascat + 2560, bv, 512*4,  hipMemcpyDeviceToDevice, stream);

  k_ropetab<<<S_, 64, 0, stream>>>(tab);
  k_rmsnorm<<<T_, 256, 0, stream>>>(x, inlnw, h2);

  // QKV: logical K=6144 (192 BK32 iters) over (hi,lo) storage
  k_gemm_d<192><<<dim3(24,16), 256, 0, stream>>>(h2, wqkv2, qkvp0, NQKV_);

  k_ropenorm<<<(T_*24)/4, 256, 0, stream>>>(qkvp0, biascat, qnw, knw, tab, Qb2, Kn2, Vt2);

  k_attn<<<dim3(S_/64, HQ_, B_), 256, 0, stream>>>(Qb2, Kn2, Vt2, attno2);

  // WO: logical K=6144 over (hi,lo) storage
  k_gemm_d<192><<<dim3(16,16), 256, 0, stream>>>(attno2, wo2, wop, H_);

  // xa = x + wop; ht = rmsnorm(xa)*postln
  k_add_rmsnorm<<<T_, 256, 0, stream>>>(x, wop, postln, xa, ht_b, ht_f);

  hipMemsetAsync(counts, 0, 32*4, stream);
  k_router<<<T_/4, 256, 0, stream>>>(ht_f, gatew, gateb, tok_e, tok_w, counts);
  k_scan<<<1, 64, 0, stream>>>(counts, segStart, segCount, cursor, tileSeg, tileMb, meta);
  k_scatter<<<(T_+255)/256, 256, 0, stream>>>(tok_e, tok_w, cursor, assignTS, assignW);

  // MoE gate/up: grouped B-dbuf pipeline, K=2048, grid (tiles, n) for B-slice L2 reuse
  k_gemm_g<2><<<dim3(MAXTILE,16), 256, 0, stream>>>(ht_b, wgu_t, inter,
      H_, (long)2048*2048, segStart, segCount, tileSeg, tileMb, meta, assignTS, assignW, nullptr);

  // MoE down: grouped B-dbuf pipeline, K=1024, grid (tiles, n)
  k_gemm_g<3><<<dim3(MAXTILE,16), 256, 0, stream>>>(inter, wd_t, nullptr,
      I_, (long)2048*1024, segStart, segCount, tileSeg, tileMb, meta, assignTS, assignW, downb);

  k_final<<<(T_*H_/4)/256, 256, 0, stream>>>(xa, downb, out);
}

// Round 17
// 827.358 us; speedup vs baseline: 1.1049x; 1.1049x over previous
//
#include <hip/hip_runtime.h>
#include <math.h>

typedef unsigned short u16;
typedef __attribute__((ext_vector_type(8))) short short8;
typedef __attribute__((ext_vector_type(4))) float f32x4;

#define B_ 2
#define S_ 1024
#define H_ 2048
#define DH_ 128
#define HQ_ 16
#define HKV_ 4
#define E_ 16
#define TOPK_ 4
#define I_ 1024
#define T_ (B_*S_)
#define NQKV_ 3072
#define NSEG_ 17
#define NA_ (T_*TOPK_ + T_)   /* 10240 assignments incl. shared */
#define K3_ 6144              /* logical 3*H for bf16x2 split GEMMs */
#define K2_ 4096              /* physical (hi,lo) row stride */
#define MAXTILE 97

#define QPLANE ((long)B_*HQ_*S_*DH_)   /* 4194304 */
#define KPLANE ((long)B_*HKV_*S_*DH_)  /* 1048576 */
#define VPLANE ((long)B_*HKV_*DH_*S_)  /* 1048576 */

// ---------------- numeric helpers ----------------
__device__ __forceinline__ float bf2f(u16 u){
  union { unsigned int i; float f; } x; x.i = ((unsigned int)u) << 16; return x.f;
}
__device__ __forceinline__ u16 f2bf(float f){
  union { float f; unsigned int i; } x; x.f = f;
  unsigned int r = x.i + 0x7fffu + ((x.i >> 16) & 1u);
  return (u16)(r >> 16);
}
__device__ __forceinline__ void split_bf(float v, u16& hi, u16& lo){
  hi = f2bf(v);
  lo = f2bf(v - bf2f(hi));
}

__device__ __forceinline__ void gld_lds16(const void* g, void* l){
  __builtin_amdgcn_global_load_lds(
      (const __attribute__((address_space(1))) unsigned int*)g,
      (__attribute__((address_space(3))) unsigned int*)l, 16, 0, 0);
}

__device__ __forceinline__ f32x4 mfma_bf16(short8 a, short8 b, f32x4 c){
  return __builtin_amdgcn_mfma_f32_16x16x32_bf16(a, b, c, 0, 0, 0);
}

// ---------------- weight transpose fp32 -> bf16 [N][K] (optional hi/lo split: row = (hi,lo), 2R) ----------------
__global__ void k_transpose(const float* __restrict__ in, u16* __restrict__ out,
                            int R, int C, int rowMul, int rowOff,
                            long inBatch, long outBatch, int split3)
{
  __shared__ float tile[64][65];
  const float* inp = in + (long)blockIdx.z * inBatch;
  u16* outp = out + (long)blockIdx.z * outBatch;
  int c0 = blockIdx.x * 64, r0 = blockIdx.y * 64;
  int tid = threadIdx.x;           // 256 threads
  int qc = (tid & 15) * 4;         // col quad within tile (read)
  int rr = tid >> 4;               // 0..15
#pragma unroll
  for (int p = 0; p < 4; p++){
    int r = p*16 + rr;
    float4 v = *(const float4*)(inp + (long)(r0 + r)*C + c0 + qc);
    tile[r][qc] = v.x; tile[r][qc+1] = v.y; tile[r][qc+2] = v.z; tile[r][qc+3] = v.w;
  }
  __syncthreads();
  int rl = (tid & 15) * 4;         // row quad within tile (write)
  int cw = tid >> 4;               // 0..15
#pragma unroll
  for (int p = 0; p < 4; p++){
    int c = p*16 + cw;
    float v0 = tile[rl][c], v1 = tile[rl+1][c], v2 = tile[rl+2][c], v3 = tile[rl+3][c];
    if (split3){
      ushort4 hi, lo;
      split_bf(v0, hi.x, lo.x); split_bf(v1, hi.y, lo.y);
      split_bf(v2, hi.z, lo.z); split_bf(v3, hi.w, lo.w);
      long base = (long)((c0 + c)*rowMul + rowOff) * (2*R) + r0 + rl;
      *(ushort4*)(outp + base)     = hi;
      *(ushort4*)(outp + base + R) = lo;
    } else {
      ushort4 hi = { f2bf(v0), f2bf(v1), f2bf(v2), f2bf(v3) };
      *(ushort4*)(outp + (long)((c0 + c)*rowMul + rowOff) * R + r0 + rl) = hi;
    }
  }
}

// ---------------- RMSNorm over H=2048 ((hi,lo) A-layout out, row K2_) ----------------
__global__ void k_rmsnorm(const float* __restrict__ x, const float* __restrict__ w,
                          u16* __restrict__ out2)
{
  int t = blockIdx.x;
  const float4* r4 = (const float4*)(x + (long)t * H_);
  const float4* w4 = (const float4*)w;
  float4 a = r4[threadIdx.x], b = r4[threadIdx.x + 256];
  float ss = a.x*a.x + a.y*a.y + a.z*a.z + a.w*a.w
           + b.x*b.x + b.y*b.y + b.z*b.z + b.w*b.w;
#pragma unroll
  for (int d = 1; d < 64; d <<= 1) ss += __shfl_xor(ss, d);
  __shared__ float red[4];
  int lane = threadIdx.x & 63, wv = threadIdx.x >> 6;
  if (lane == 0) red[wv] = ss;
  __syncthreads();
  ss = red[0] + red[1] + red[2] + red[3];
  float rs = rsqrtf(ss * (1.f / 2048.f) + 1e-5f);
  float4 wa = w4[threadIdx.x], wb = w4[threadIdx.x + 256];
  float va[8] = { a.x*rs*wa.x, a.y*rs*wa.y, a.z*rs*wa.z, a.w*rs*wa.w,
                  b.x*rs*wb.x, b.y*rs*wb.y, b.z*rs*wb.z, b.w*rs*wb.w };
  int pos0 = threadIdx.x*4, pos1 = 1024 + threadIdx.x*4;
  ushort4 hi0, lo0, hi1, lo1;
  split_bf(va[0], hi0.x, lo0.x); split_bf(va[1], hi0.y, lo0.y);
  split_bf(va[2], hi0.z, lo0.z); split_bf(va[3], hi0.w, lo0.w);
  split_bf(va[4], hi1.x, lo1.x); split_bf(va[5], hi1.y, lo1.y);
  split_bf(va[6], hi1.z, lo1.z); split_bf(va[7], hi1.w, lo1.w);
  u16* row = out2 + (long)t * K2_;
  *(ushort4*)(row + pos0) = hi0;        *(ushort4*)(row + pos1) = hi1;
  *(ushort4*)(row + 2048 + pos0) = lo0; *(ushort4*)(row + 2048 + pos1) = lo1;
}

// ---------------- WO + residual + RMSNorm fused ----------------
__global__ void k_add_rmsnorm(const float* __restrict__ x, const float* __restrict__ p0,
                              const float* __restrict__ w, float* __restrict__ xa,
                              u16* __restrict__ out1, float* __restrict__ outf)
{
  int t = blockIdx.x;
  long base = (long)t * H_;
  const float4* x4 = (const float4*)(x + base);
  const float4* a4 = (const float4*)(p0 + base);
  const float4* w4 = (const float4*)w;
  int i0 = threadIdx.x, i1 = threadIdx.x + 256;
  float4 xv0 = x4[i0], xv1 = x4[i1];
  float4 av0 = a4[i0], av1 = a4[i1];
  float4 s0, s1;
  s0.x = xv0.x+av0.x; s0.y = xv0.y+av0.y; s0.z = xv0.z+av0.z; s0.w = xv0.w+av0.w;
  s1.x = xv1.x+av1.x; s1.y = xv1.y+av1.y; s1.z = xv1.z+av1.z; s1.w = xv1.w+av1.w;
  *(float4*)(xa + base + i0*4) = s0;
  *(float4*)(xa + base + i1*4) = s1;
  float ss = s0.x*s0.x + s0.y*s0.y + s0.z*s0.z + s0.w*s0.w
           + s1.x*s1.x + s1.y*s1.y + s1.z*s1.z + s1.w*s1.w;
#pragma unroll
  for (int d = 1; d < 64; d <<= 1) ss += __shfl_xor(ss, d);
  __shared__ float red[4];
  int lane = threadIdx.x & 63, wv = threadIdx.x >> 6;
  if (lane == 0) red[wv] = ss;
  __syncthreads();
  ss = red[0] + red[1] + red[2] + red[3];
  float rs = rsqrtf(ss * (1.f / 2048.f) + 1e-5f);
  float4 wa = w4[i0], wb = w4[i1];
  float va[8] = { s0.x*rs*wa.x, s0.y*rs*wa.y, s0.z*rs*wa.z, s0.w*rs*wa.w,
                  s1.x*rs*wb.x, s1.y*rs*wb.y, s1.z*rs*wb.z, s1.w*rs*wb.w };
  ushort4 q0 = { f2bf(va[0]), f2bf(va[1]), f2bf(va[2]), f2bf(va[3]) };
  ushort4 q1 = { f2bf(va[4]), f2bf(va[5]), f2bf(va[6]), f2bf(va[7]) };
  *(ushort4*)(out1 + base + i0*4) = q0;
  *(ushort4*)(out1 + base + i1*4) = q1;
  float4 oa = { va[0], va[1], va[2], va[3] };
  float4 ob = { va[4], va[5], va[6], va[7] };
  *(float4*)(outf + base + i0*4) = oa;
  *(float4*)(outf + base + i1*4) = ob;
}

// ---------------- RoPE table (fp64) ----------------
__global__ void k_ropetab(float* __restrict__ tab){
  int s = blockIdx.x, i = threadIdx.x; // 64 threads
  double inv = pow(10000.0, -(double)i / 64.0);
  double fr = (double)s * inv;
  tab[s*128 + i]      = (float)cos(fr);
  tab[s*128 + 64 + i] = (float)sin(fr);
}

// ---------------- per-head QK norm + RoPE + hi/lo split layout ----------------
__global__ void k_ropenorm(const float* __restrict__ qkv, const float* __restrict__ biascat,
                           const float* __restrict__ qnw, const float* __restrict__ knw,
                           const float* __restrict__ tab,
                           u16* __restrict__ Q, u16* __restrict__ Kn, u16* __restrict__ Vt)
{
  long gw = (long)blockIdx.x * 4 + (threadIdx.x >> 6);
  int lane = threadIdx.x & 63;
  int hr = (int)(gw % 24);
  long bs = gw / 24;            // token index t = b*S + s
  int s = (int)(bs % S_);
  int b = (int)(bs / S_);
  long ro = bs * NQKV_ + hr * DH_;
  float x1 = qkv[ro + lane] + biascat[hr*DH_ + lane];
  float x2 = qkv[ro + lane + 64] + biascat[hr*DH_ + lane + 64];
  if (hr < 20){
    float ss = x1*x1 + x2*x2;
#pragma unroll
    for (int d = 1; d < 64; d <<= 1) ss += __shfl_xor(ss, d);
    float rs = rsqrtf(ss * (1.f/128.f) + 1e-5f);
    const float* wn = (hr < 16) ? qnw : knw;
    float y1 = x1 * rs * wn[lane], y2 = x2 * rs * wn[lane + 64];
    float c = tab[s*128 + lane], sn = tab[s*128 + 64 + lane];
    float o1 = y1*c - y2*sn, o2 = y2*c + y1*sn;
    if (hr < 16){
      const float sc = 0.088388347648318447f; // 1/sqrt(128)
      u16 h1,l1,h2,l2;
      split_bf(o1*sc, h1, l1); split_bf(o2*sc, h2, l2);
      u16* dst = Q + (((long)b*HQ_ + hr)*S_ + s) * DH_;
      dst[lane] = h1; dst[lane+64] = h2;
      dst[QPLANE + lane] = l1; dst[QPLANE + lane+64] = l2;
    } else {
      u16 h1,l1,h2,l2;
      split_bf(o1, h1, l1); split_bf(o2, h2, l2);
      u16* dst = Kn + (((long)b*HKV_ + (hr-16))*S_ + s) * DH_;
      dst[lane] = h1; dst[lane+64] = h2;
      dst[KPLANE + lane] = l1; dst[KPLANE + lane+64] = l2;
    }
  } else {
    u16 h1,l1,h2,l2;
    split_bf(x1, h1, l1); split_bf(x2, h2, l2);
    u16* dst = Vt + (((long)b*HKV_ + (hr-20))*DH_) * S_ + s;
    dst[(long)lane * S_]        = h1;
    dst[(long)(lane + 64) * S_] = h2;
    dst[VPLANE + (long)lane * S_]        = l1;
    dst[VPLANE + (long)(lane + 64) * S_] = l2;
  }
}

// ---------------- flash attention (causal, GQA 4:1), bf16x2 3-term MFMA ----------------
__launch_bounds__(256)
__global__ void k_attn(const u16* __restrict__ Q, const u16* __restrict__ Kn,
                       const u16* __restrict__ Vt, u16* __restrict__ O2)
{
  __shared__ u16 LDS[2*16384];
  int qb = (gridDim.x - 1) - blockIdx.x;   // longest blocks first (LPT)
  int h = blockIdx.y, b = blockIdx.z;
  int kvh = h >> 2;
  int q0 = qb * 64;
  int tid = threadIdx.x, lane = tid & 63, w = tid >> 6;

  const u16* Qg = Q  + (((long)b*HQ_  + h  )*S_ + q0) * DH_;
  const u16* Kg = Kn + (((long)b*HKV_ + kvh)*S_) * DH_;
  const u16* Vg = Vt + (((long)b*HKV_ + kvh)*DH_) * S_;

  short8 qh[4], ql[4];
  {
    long qrow = w*16 + (lane & 15);
    int coff = (lane >> 4) << 3;
#pragma unroll
    for (int kst = 0; kst < 4; kst++){
      qh[kst] = *(const short8*)(Qg + qrow*DH_ + kst*32 + coff);
      ql[kst] = *(const short8*)(Qg + QPLANE + qrow*DH_ + kst*32 + coff);
    }
  }

  long ksrc[2]; int kdst[2];
  long vsrc[2]; int vdst[2];
#pragma unroll
  for (int it = 0; it < 2; ++it){
    {
      int flat = it*256 + tid;
      int r = flat >> 4, pc = flat & 15;
      int c = pc ^ (((r&7) << 1) | ((r >> 3) & 1));
      ksrc[it] = (long)r*DH_ + c*8;
      kdst[it] = (it*256 + (w<<6))*8;
    }
    {
      int flat = it*256 + tid;
      int r = flat >> 2, pc = flat & 3;
      int c = pc ^ (r & 3);
      vsrc[it] = (long)r*S_ + c*8;
      vdst[it] = 8192 + (it*256 + (w<<6))*8;
    }
  }

  auto STAGE_K = [&](int jj){
    int bo = (jj & 1) * 16384;
    long joff = (long)jj*32*DH_;
#pragma unroll
    for (int it = 0; it < 2; ++it){
      gld_lds16(Kg + ksrc[it] + joff,          &LDS[bo + kdst[it]]);
      gld_lds16(Kg + KPLANE + ksrc[it] + joff, &LDS[bo + 4096 + kdst[it]]);
    }
  };
  auto STAGE_V = [&](int jj){
    int bo = (jj & 1) * 16384;
    long joff = (long)jj*32;
#pragma unroll
    for (int it = 0; it < 2; ++it){
      gld_lds16(Vg + vsrc[it] + joff,          &LDS[bo + vdst[it]]);
      gld_lds16(Vg + VPLANE + vsrc[it] + joff, &LDS[bo + 4096 + vdst[it]]);
    }
  };

  f32x4 o[8];
#pragma unroll
  for (int nt = 0; nt < 8; nt++) o[nt] = (f32x4){0.f,0.f,0.f,0.f};
  float mrow[4] = {-INFINITY,-INFINITY,-INFINITY,-INFINITY};
  float lrow[4] = {0.f,0.f,0.f,0.f};

  int jmax = 2*qb + 1;
  STAGE_K(0);
  STAGE_V(0);

  for (int j = 0; j <= jmax; ++j){
    if (j < jmax){
      STAGE_K(j+1);
      asm volatile("s_waitcnt vmcnt(8)" ::: "memory");
    } else {
      asm volatile("s_waitcnt vmcnt(4)" ::: "memory");
    }
    __builtin_amdgcn_s_barrier();
    __builtin_amdgcn_sched_barrier(0);

    const u16* Lb = &LDS[(j & 1) * 16384];
    u16* Pb = &LDS[((j + 1) & 1) * 16384 + 8192];

    f32x4 s[2];
#pragma unroll
    for (int nt = 0; nt < 2; nt++) s[nt] = (f32x4){0.f,0.f,0.f,0.f};
#pragma unroll
    for (int kst = 0; kst < 4; kst++){
#pragma unroll
      for (int nt = 0; nt < 2; nt++){
        int br = nt*16 + (lane & 15);
        int bc = (kst*4 + (lane >> 4)) ^ (((br&7)<<1) | ((br>>3)&1));
        short8 kh = *(const short8*)(Lb + br*128 + bc*8);
        short8 kl = *(const short8*)(Lb + 4096 + br*128 + bc*8);
        s[nt] = mfma_bf16(qh[kst], kh, s[nt]);
        s[nt] = mfma_bf16(qh[kst], kl, s[nt]);
        s[nt] = mfma_bf16(ql[kst], kh, s[nt]);
      }
    }
    if (j >= 2*qb){
#pragma unroll
      for (int nt = 0; nt < 2; nt++){
        int key = j*32 + nt*16 + (lane & 15);
#pragma unroll
        for (int r = 0; r < 4; r++){
          int qrow = q0 + w*16 + ((lane >> 4) << 2) + r;
          if (key > qrow) s[nt][r] = -1e30f;
        }
      }
    }
    float pm[4];
#pragma unroll
    for (int r = 0; r < 4; r++) pm[r] = fmaxf(s[0][r], s[1][r]);
#pragma unroll
    for (int d = 1; d < 16; d <<= 1){
#pragma unroll
      for (int r = 0; r < 4; r++) pm[r] = fmaxf(pm[r], __shfl_xor(pm[r], d));
    }
    float alpha[4];
#pragma unroll
    for (int r = 0; r < 4; r++){
      float mn = fmaxf(mrow[r], pm[r]);
      alpha[r] = __expf(mrow[r] - mn);
      mrow[r] = mn;
    }
    float psum[4] = {0.f,0.f,0.f,0.f};
#pragma unroll
    for (int nt = 0; nt < 2; nt++){
#pragma unroll
      for (int r = 0; r < 4; r++){
        float p = __expf(s[nt][r] - mrow[r]);
        psum[r] += p;
        u16 ph, pl; split_bf(p, ph, pl);
        int qr = ((lane>>4)<<2) + r, kc = nt*16 + (lane & 15);
        Pb[w*640 + qr*40 + kc]        = ph;
        Pb[2560 + w*640 + qr*40 + kc] = pl;
      }
    }
#pragma unroll
    for (int d = 1; d < 16; d <<= 1){
#pragma unroll
      for (int r = 0; r < 4; r++) psum[r] += __shfl_xor(psum[r], d);
    }
#pragma unroll
    for (int r = 0; r < 4; r++) lrow[r] = lrow[r]*alpha[r] + psum[r];
#pragma unroll
    for (int nt = 0; nt < 8; nt++)
#pragma unroll
      for (int r = 0; r < 4; r++) o[nt][r] *= alpha[r];

    if (j < jmax) asm volatile("s_waitcnt vmcnt(4)" ::: "memory");
    else          asm volatile("s_waitcnt vmcnt(0)" ::: "memory");
    __builtin_amdgcn_s_barrier();
    __builtin_amdgcn_sched_barrier(0);

    {
      short8 pah = *(const short8*)(Pb + w*640 + (lane & 15)*40 + ((lane >> 4) << 3));
      short8 pal = *(const short8*)(Pb + 2560 + w*640 + (lane & 15)*40 + ((lane >> 4) << 3));
#pragma unroll
      for (int nt = 0; nt < 8; nt++){
        int br = nt*16 + (lane & 15);
        int bc = (lane >> 4) ^ (br & 3);
        short8 vh = *(const short8*)(Lb + 8192 + br*32 + bc*8);
        short8 vl = *(const short8*)(Lb + 12288 + br*32 + bc*8);
        o[nt] = mfma_bf16(pah, vh, o[nt]);
        o[nt] = mfma_bf16(pah, vl, o[nt]);
        o[nt] = mfma_bf16(pal, vh, o[nt]);
      }
    }
    asm volatile("s_waitcnt lgkmcnt(0)" ::: "memory");
    __builtin_amdgcn_sched_barrier(0);
    __builtin_amdgcn_s_barrier();
    if (j < jmax) STAGE_V(j+1);
  }

  float inv_[4];
#pragma unroll
  for (int r = 0; r < 4; r++) inv_[r] = 1.f / lrow[r];
#pragma unroll
  for (int nt = 0; nt < 8; nt++){
#pragma unroll
    for (int r = 0; r < 4; r++){
      long row = (long)b*S_ + q0 + w*16 + ((lane >> 4) << 2) + r;
      float val = o[nt][r] * inv_[r];
      u16 hi, lo; split_bf(val, hi, lo);
      long base = row*K2_ + h*DH_ + nt*16 + (lane & 15);
      O2[base]        = hi;
      O2[base + 2048] = lo;
    }
  }
}

// ---------------- dense pipelined 128x128 GEMM (BK=32, 4-deep LDS, counted vmcnt) ----------------
template<int KITERS>
__launch_bounds__(256)
__global__ void k_gemm_d(const u16* __restrict__ A, const u16* __restrict__ Bm,
                         float* __restrict__ C, int N)
{
  __shared__ u16 LDS[4*8192];
  int tid = threadIdx.x;
  int lane = tid & 63, w = tid >> 6;
  int wr = w >> 1, wc = w & 1;
  int n0 = blockIdx.x * 128;
  int m0 = blockIdx.y * 128;

  const u16* aS[2]; const u16* bS[2];
#pragma unroll
  for (int it = 0; it < 2; ++it){
    int c = w + it*4;
    int row = c*16 + (lane >> 2);
    int ps = (lane & 3) ^ ((row >> 1) & 3);
    aS[it] = A + (long)(m0 + row) * K2_ + ps*8;
    bS[it] = Bm + (long)(n0 + row) * K2_ + ps*8;
  }

  int offA[4], offB[4];
#pragma unroll
  for (int m = 0; m < 4; m++){
    int r = wr*64 + m*16 + (lane & 15);
    int ps = (lane >> 4) ^ ((r >> 1) & 3);
    offA[m] = r*32 + ps*8;
  }
#pragma unroll
  for (int n = 0; n < 4; n++){
    int r = wc*64 + n*16 + (lane & 15);
    int ps = (lane >> 4) ^ ((r >> 1) & 3);
    offB[n] = 4096 + r*32 + ps*8;
  }

  f32x4 acc[4][4];
#pragma unroll
  for (int m = 0; m < 4; m++)
#pragma unroll
    for (int n = 0; n < 4; n++) acc[m][n] = (f32x4){0.f,0.f,0.f,0.f};

  auto STAGE = [&](int Tt){
    int kb = Tt * 32;
    int kA = (kb < 2048) ? kb : kb - 2048;
    int kB = (kb < 4096) ? kb : kb - 4096;
    int db = (Tt & 3) * 8192;
#pragma unroll
    for (int it = 0; it < 2; ++it){
      gld_lds16(aS[it] + kA, &LDS[db + (w + it*4)*512]);
      gld_lds16(bS[it] + kB, &LDS[db + 4096 + (w + it*4)*512]);
    }
  };

  STAGE(0); STAGE(1); STAGE(2);

  for (int T = 0; T < KITERS; ++T){
    if (T + 3 < KITERS) STAGE(T + 3);
    int rem = KITERS - 1 - T;
    if (rem >= 3)      asm volatile("s_waitcnt vmcnt(12)" ::: "memory");
    else if (rem == 2) asm volatile("s_waitcnt vmcnt(8)"  ::: "memory");
    else if (rem == 1) asm volatile("s_waitcnt vmcnt(4)"  ::: "memory");
    else               asm volatile("s_waitcnt vmcnt(0)"  ::: "memory");
    __builtin_amdgcn_s_barrier();
    __builtin_amdgcn_sched_barrier(0);
    const u16* L = &LDS[(T & 3) * 8192];
    short8 af[4], bfv[4];
#pragma unroll
    for (int m = 0; m < 4; m++) af[m]  = *(const short8*)(L + offA[m]);
#pragma unroll
    for (int n = 0; n < 4; n++) bfv[n] = *(const short8*)(L + offB[n]);
#pragma unroll
    for (int m = 0; m < 4; m++)
#pragma unroll
      for (int n = 0; n < 4; n++)
        acc[m][n] = mfma_bf16(af[m], bfv[n], acc[m][n]);
    asm volatile("s_waitcnt lgkmcnt(0)" ::: "memory");
    __builtin_amdgcn_sched_barrier(0);
    __builtin_amdgcn_s_barrier();
  }

#pragma unroll
  for (int m = 0; m < 4; m++){
    int row0 = m0 + wr*64 + m*16 + ((lane >> 4) << 2);
#pragma unroll
    for (int n = 0; n < 4; n++){
      int col = n0 + wc*64 + n*16 + (lane & 15);
#pragma unroll
      for (int r = 0; r < 4; r++)
        C[(long)(row0 + r)*N + col] = acc[m][n][r];
    }
  }
}

// ---------------- grouped 128x128 GEMM, BK=64, B-only double-buffer (48KB LDS) ----------------
// Grid (16 n-blocks, tiles) x-major — R14-proven: same-expert m-tiles sit 16 apart in
// flat id -> same XCD (16%8==0) -> private-L2 B reuse (measured FETCH 206MB vs 516MB swapped).
template<int MODE>
__launch_bounds__(256)
__global__ void k_gemm_g(const u16* __restrict__ A, const u16* __restrict__ Bm,
                         void* __restrict__ Cout,
                         int Kloop, long segStrideB,
                         const int* __restrict__ segStart, const int* __restrict__ segCount,
                         const int* __restrict__ tileSeg, const int* __restrict__ tileMb,
                         const int* __restrict__ meta,
                         const int* __restrict__ assignTS, const float* __restrict__ assignW,
                         u16* __restrict__ downb)
{
  __shared__ u16 LDS[3*8192];   // A: [0,8192), B0: [8192,16384), B1: [16384,24576)
  int tid = threadIdx.x;
  int lane = tid & 63, w = tid >> 6;
  int wr = w >> 1, wc = w & 1;
  int n0 = blockIdx.x * 128;
  int ty = blockIdx.y;
  if (ty >= meta[0]) return;
  int seg = tileSeg[ty], m0 = tileMb[ty] * 128;
  int segBase = segStart[seg];
  int cnt = segCount[seg];
  const u16* Bp = Bm + (long)seg * segStrideB;

  const u16* aS[4]; const u16* bS[4];
#pragma unroll
  for (int it = 0; it < 4; ++it){
    int flat = it*256 + tid;
    int r = flat >> 3, pc = flat & 7;
    int c = pc ^ (r & 7);
    long arow;
    if constexpr (MODE == 2) arow = (long)(assignTS[segBase + m0 + r] >> 3);
    else arow = (long)(segBase + m0 + r);
    aS[it] = A + arow * Kloop + c*8;
    bS[it] = Bp + (long)(n0 + r) * Kloop + c*8;
  }

  auto STAGE_A = [&](int Tt){
    int kb = Tt * 64;
#pragma unroll
    for (int it = 0; it < 4; ++it)
      gld_lds16(aS[it] + kb, &LDS[(it*256 + (w<<6))*8]);
  };
  auto STAGE_B = [&](int Tt){
    int kb = Tt * 64;
    int bb = 8192 + (Tt & 1)*8192;
#pragma unroll
    for (int it = 0; it < 4; ++it)
      gld_lds16(bS[it] + kb, &LDS[bb + (it*256 + (w<<6))*8]);
  };

  f32x4 acc[4][4];
#pragma unroll
  for (int m = 0; m < 4; m++)
#pragma unroll
    for (int n = 0; n < 4; n++) acc[m][n] = (f32x4){0.f,0.f,0.f,0.f};

  int NT = Kloop >> 6;
  STAGE_A(0); STAGE_B(0);

  for (int T = 0; T < NT; ++T){
    if (T + 1 < NT){
      STAGE_B(T + 1);
      asm volatile("s_waitcnt vmcnt(4)" ::: "memory");   // A(T)+B(T) landed; B(T+1) in flight
    } else {
      asm volatile("s_waitcnt vmcnt(0)" ::: "memory");
    }
    __builtin_amdgcn_s_barrier();
    __builtin_amdgcn_sched_barrier(0);
    const u16* Bb = &LDS[8192 + (T & 1)*8192];
#pragma unroll
    for (int kh = 0; kh < 2; ++kh){
      short8 af[4], bfv[4];
#pragma unroll
      for (int m = 0; m < 4; m++){
        int r = wr*64 + m*16 + (lane & 15);
        int c = (kh*4 + (lane >> 4)) ^ (r & 7);
        af[m] = *(const short8*)(&LDS[0] + r*64 + c*8);
      }
#pragma unroll
      for (int n = 0; n < 4; n++){
        int r = wc*64 + n*16 + (lane & 15);
        int c = (kh*4 + (lane >> 4)) ^ (r & 7);
        bfv[n] = *(const short8*)(Bb + r*64 + c*8);
      }
#pragma unroll
      for (int m = 0; m < 4; m++)
#pragma unroll
        for (int n = 0; n < 4; n++)
          acc[m][n] = mfma_bf16(af[m], bfv[n], acc[m][n]);
    }
    asm volatile("s_waitcnt lgkmcnt(0)" ::: "memory");
    __builtin_amdgcn_sched_barrier(0);
    __builtin_amdgcn_s_barrier();
    if (T + 1 < NT) STAGE_A(T + 1);   // A-buf readers done (lgkm drained + barrier)
  }

  if constexpr (MODE == 2){
    u16* inter = (u16*)Cout;
#pragma unroll
    for (int m = 0; m < 4; m++){
      int row0 = m0 + wr*64 + m*16 + ((lane >> 4) << 2);
#pragma unroll
      for (int n = 0; n < 4; n++){
        f32x4 a = acc[m][n];
        float ov[4];
#pragma unroll
        for (int r = 0; r < 4; r++) ov[r] = __shfl_xor(a[r], 1);
        if ((lane & 1) == 0){
          int colp = (n0 + wc*64 + n*16 + (lane & 15)) >> 1;
#pragma unroll
          for (int r = 0; r < 4; r++){
            int rl = row0 + r;
            if (rl < cnt){
              int pos = segBase + rl;
              float g = a[r], u = ov[r];
              float val = (g / (1.f + __expf(-g))) * u * assignW[pos];
              inter[(long)pos*I_ + colp] = f2bf(val);
            }
          }
        }
      }
    }
  } else {
#pragma unroll
    for (int m = 0; m < 4; m++){
      int row0 = m0 + wr*64 + m*16 + ((lane >> 4) << 2);
#pragma unroll
      for (int n = 0; n < 4; n++){
        int col = n0 + wc*64 + n*16 + (lane & 15);
#pragma unroll
        for (int r = 0; r < 4; r++){
          int rl = row0 + r;
          if (rl < cnt){
            int ts = assignTS[segBase + rl];
            downb[((long)(ts >> 3)*5 + (ts & 7))*H_ + col] = f2bf(acc[m][n][r]);
          }
        }
      }
    }
  }
}

// ---------------- router (fp32, wave-per-token, streamed row / all-expert acc) ----------------
__global__ void k_router(const float* __restrict__ ht, const float* __restrict__ gw,
                         const float* __restrict__ gb, int* __restrict__ tok_e,
                         float* __restrict__ tok_w, int* __restrict__ counts)
{
  int t = blockIdx.x * 4 + (threadIdx.x >> 6);
  int lane = threadIdx.x & 63;
  const float4* row4 = (const float4*)(ht + (long)t * H_);
  float acc[16];
#pragma unroll
  for (int e = 0; e < 16; e++) acc[e] = 0.f;
#pragma unroll
  for (int it = 0; it < 8; it++){
    float4 rv = row4[lane + 64*it];
#pragma unroll
    for (int e = 0; e < 16; e++){
      float4 gv = *(const float4*)(gw + (long)e*H_ + (lane + 64*it)*4);
      acc[e] += rv.x*gv.x + rv.y*gv.y + rv.z*gv.z + rv.w*gv.w;
    }
  }
#pragma unroll
  for (int d = 1; d < 64; d <<= 1){
#pragma unroll
    for (int e = 0; e < 16; e++) acc[e] += __shfl_xor(acc[e], d);
  }
  if (lane == 0){
    float scr[16], ch[16];
#pragma unroll
    for (int e = 0; e < 16; e++){
      float s = 1.f / (1.f + __expf(-acc[e]));
      scr[e] = s; ch[e] = s + gb[e];
    }
    int sel[4]; float tw[4]; float sum = 0.f;
#pragma unroll
    for (int k = 0; k < 4; k++){
      int best = -1; float bv = -1e30f;
      for (int e = 0; e < 16; e++){
        bool used = false;
        for (int j = 0; j < k; j++) if (sel[j] == e) used = true;
        if (!used && ch[e] > bv){ bv = ch[e]; best = e; }
      }
      sel[k] = best; tw[k] = scr[best]; sum += scr[best];
    }
    float inv = 1.f / (sum + 1e-20f);
#pragma unroll
    for (int k = 0; k < 4; k++){
      tok_e[t*4 + k] = sel[k];
      tok_w[t*4 + k] = tw[k] * inv;
      atomicAdd(&counts[sel[k]], 1);
    }
  }
}

__global__ void k_scan(const int* __restrict__ counts, int* __restrict__ segStart,
                       int* __restrict__ segCount, int* __restrict__ cursor,
                       int* __restrict__ tileSeg, int* __restrict__ tileMb,
                       int* __restrict__ meta)
{
  if (threadIdx.x == 0){
    int off = 0, nt = 0;
    for (int e = 0; e < 16; e++){
      segStart[e] = off; segCount[e] = counts[e]; cursor[e] = off;
      for (int mb = 0; mb*128 < counts[e]; ++mb){ tileSeg[nt] = e; tileMb[nt] = mb; nt++; }
      off += counts[e];
    }
    segStart[16] = T_*TOPK_; segCount[16] = T_;
    for (int mb = 0; mb < 16; ++mb){ tileSeg[nt] = 16; tileMb[nt] = mb; nt++; }
    meta[0] = nt;
  }
}

__global__ void k_scatter(const int* __restrict__ tok_e, const float* __restrict__ tok_w,
                          int* __restrict__ cursor, int* __restrict__ assignTS,
                          float* __restrict__ assignW)
{
  int t = blockIdx.x*256 + threadIdx.x;
  if (t < T_){
    for (int k = 0; k < 4; k++){
      int e = tok_e[t*4 + k];
      int pos = atomicAdd(&cursor[e], 1);
      assignTS[pos] = t*8 + k;
      assignW[pos] = tok_w[t*4 + k];
    }
    assignTS[T_*TOPK_ + t] = t*8 + 4;
    assignW[T_*TOPK_ + t] = 1.f;
  }
}

// ---------------- final: out = xa + sum_slots down ----------------
__global__ void k_final(const float* __restrict__ xa, const u16* __restrict__ downb,
                        float* __restrict__ out)
{
  long i = ((long)blockIdx.x*256 + threadIdx.x) * 4;
  int t = (int)(i >> 11);
  int h = (int)(i & 2047);
  float4 r = *(const float4*)(xa + i);
  float a0 = r.x, a1 = r.y, a2 = r.z, a3 = r.w;
#pragma unroll
  for (int k = 0; k < 5; k++){
    const u16* d = downb + ((long)t*5 + k)*H_ + h;
    ushort4 v = *(const ushort4*)d;
    a0 += bf2f(v.x); a1 += bf2f(v.y); a2 += bf2f(v.z); a3 += bf2f(v.w);
  }
  float4 o = { a0, a1, a2, a3 };
  *(float4*)(out + i) = o;
}

// ---------------- host ----------------
extern "C" void kernel_launch(void* const* d_in, const int* in_sizes, int n_in,
                              void* d_out, int out_size, void* d_ws, size_t ws_size,
                              hipStream_t stream)
{
  (void)in_sizes; (void)n_in; (void)out_size; (void)ws_size;
  const float* x      = (const float*)d_in[0];
  const float* inlnw  = (const float*)d_in[1];
  const float* wq     = (const float*)d_in[2];
  const float* bq     = (const float*)d_in[3];
  const float* wk     = (const float*)d_in[4];
  const float* bk     = (const float*)d_in[5];
  const float* wv     = (const float*)d_in[6];
  const float* bv     = (const float*)d_in[7];
  const float* qnw    = (const float*)d_in[8];
  const float* knw    = (const float*)d_in[9];
  const float* wo     = (const float*)d_in[10];
  const float* postln = (const float*)d_in[11];
  const float* gatew  = (const float*)d_in[12];
  const float* gateb  = (const float*)d_in[13];
  const float* wg     = (const float*)d_in[14];
  const float* wu     = (const float*)d_in[15];
  const float* wdp    = (const float*)d_in[16];
  const float* swg    = (const float*)d_in[17];
  const float* swu    = (const float*)d_in[18];
  const float* swd    = (const float*)d_in[19];
  float* out = (float*)d_out;

  char* ws = (char*)d_ws;
  size_t off = 0;
  auto alloc = [&](size_t bytes) -> char* {
    char* p = ws + off; off += (bytes + 255) & ~(size_t)255; return p;
  };
  // persistent
  u16*   wqkv2   = (u16*)  alloc((size_t)NQKV_*K2_*2);     // 25.17 MB (hi,lo)
  u16*   wo2     = (u16*)  alloc((size_t)H_*K2_*2);        // 16.78 MB (hi,lo)
  u16*   wgu_t   = (u16*)  alloc((size_t)NSEG_*2048*2048*2); // 142.6 MB
  u16*   wd_t    = (u16*)  alloc((size_t)NSEG_*2048*1024*2); // 71.3 MB
  float* tab     = (float*)alloc((size_t)S_*128*4);
  float* biascat = (float*)alloc((size_t)NQKV_*4);
  float* xa      = (float*)alloc((size_t)T_*H_*4);         // 16.78 MB
  int*   tok_e   = (int*)  alloc((size_t)T_*4*4);
  float* tok_w   = (float*)alloc((size_t)T_*4*4);
  int*   counts  = (int*)  alloc(32*4);
  int*   segStart= (int*)  alloc(32*4);
  int*   segCount= (int*)  alloc(32*4);
  int*   cursor  = (int*)  alloc(32*4);
  int*   tileSeg = (int*)  alloc(128*4);
  int*   tileMb  = (int*)  alloc(128*4);
  int*   meta    = (int*)  alloc(32*4);
  int*   assignTS= (int*)  alloc((size_t)NA_*4);
  float* assignW = (float*)alloc((size_t)NA_*4);
  // scratch regions (re-used across phases)
  char*  scrA    = alloc((size_t)NA_*I_*2);                // 20.97 MB: h2 -> attno2 -> inter
  char*  scrBC   = alloc((size_t)2*T_*NQKV_*4);            // 50.33 MB: qkv -> wop
  char*  scrD    = alloc((size_t)(2*QPLANE + 2*KPLANE + 2*VPLANE)*2); // 25.17 MB: Q/K/V -> ht -> downb

  u16*   h2      = (u16*)scrA;
  u16*   attno2  = (u16*)scrA;
  u16*   inter   = (u16*)scrA;
  float* qkvp0   = (float*)scrBC;
  float* wop     = (float*)scrBC;
  u16*   Qb2     = (u16*)scrD;
  u16*   Kn2     = (u16*)(scrD + (size_t)2*QPLANE*2);
  u16*   Vt2     = (u16*)(scrD + (size_t)2*QPLANE*2 + (size_t)2*KPLANE*2);
  float* ht_f    = (float*)scrD;
  u16*   ht_b    = (u16*)(scrD + (size_t)T_*H_*4);
  u16*   downb   = (u16*)scrD;

  // weight conversion (64x64 tiles, 256 threads); split weights (hi,lo) 2R rows
  k_transpose<<<dim3(32,32,1),  256, 0, stream>>>(wq,  wqkv2, 2048, 2048, 1, 0,    0, 0, 1);
  k_transpose<<<dim3(8,32,1),   256, 0, stream>>>(wk,  wqkv2, 2048, 512,  1, 2048, 0, 0, 1);
  k_transpose<<<dim3(8,32,1),   256, 0, stream>>>(wv,  wqkv2, 2048, 512,  1, 2560, 0, 0, 1);
  k_transpose<<<dim3(32,32,1),  256, 0, stream>>>(wo,  wo2,   2048, 2048, 1, 0,    0, 0, 1);
  k_transpose<<<dim3(16,32,16), 256, 0, stream>>>(wg,  wgu_t, 2048, 1024, 2, 0, (long)2048*1024, (long)2048*2048, 0);
  k_transpose<<<dim3(16,32,16), 256, 0, stream>>>(wu,  wgu_t, 2048, 1024, 2, 1, (long)2048*1024, (long)2048*2048, 0);
  k_transpose<<<dim3(16,32,1),  256, 0, stream>>>(swg, wgu_t + (long)16*2048*2048, 2048, 1024, 2, 0, 0, 0, 0);
  k_transpose<<<dim3(16,32,1),  256, 0, stream>>>(swu, wgu_t + (long)16*2048*2048, 2048, 1024, 2, 1, 0, 0, 0);
  k_transpose<<<dim3(32,16,16), 256, 0, stream>>>(wdp, wd_t,  1024, 2048, 1, 0, (long)1024*2048, (long)2048*1024, 0);
  k_transpose<<<dim3(32,16,1),  256, 0, stream>>>(swd, wd_t + (long)16*2048*1024, 1024, 2048, 1, 0, 0, 0, 0);

  hipMemcpyAsync(biascat,        bq, 2048*4, hipMemcpyDeviceToDevice, stream);
  hipMemcpyAsync(biascat + 2048, bk, 512*4,  hipMemcpyDeviceToDevice, stream);
  hipMemcpyAsync(biascat + 2560, bv, 512*4,  hipMemcpyDeviceToDevice, stream);

  k_ropetab<<<S_, 64, 0, stream>>>(tab);
  k_rmsnorm<<<T_, 256, 0, stream>>>(x, inlnw, h2);

  // QKV: logical K=6144 (192 BK32 iters) over (hi,lo) storage
  k_gemm_d<192><<<dim3(24,16), 256, 0, stream>>>(h2, wqkv2, qkvp0, NQKV_);

  k_ropenorm<<<(T_*24)/4, 256, 0, stream>>>(qkvp0, biascat, qnw, knw, tab, Qb2, Kn2, Vt2);

  k_attn<<<dim3(S_/64, HQ_, B_), 256, 0, stream>>>(Qb2, Kn2, Vt2, attno2);

  // WO: logical K=6144 over (hi,lo) storage
  k_gemm_d<192><<<dim3(16,16), 256, 0, stream>>>(attno2, wo2, wop, H_);

  // xa = x + wop; ht = rmsnorm(xa)*postln
  k_add_rmsnorm<<<T_, 256, 0, stream>>>(x, wop, postln, xa, ht_b, ht_f);

  hipMemsetAsync(counts, 0, 32*4, stream);
  k_router<<<T_/4, 256, 0, stream>>>(ht_f, gatew, gateb, tok_e, tok_w, counts);
  k_scan<<<1, 64, 0, stream>>>(counts, segStart, segCount, cursor, tileSeg, tileMb, meta);
  k_scatter<<<(T_+255)/256, 256, 0, stream>>>(tok_e, tok_w, cursor, assignTS, assignW);

  // MoE gate/up: grouped B-dbuf pipeline, K=2048, grid (16 n, tiles) — R14-proven layout
  k_gemm_g<2><<<dim3(16,MAXTILE), 256, 0, stream>>>(ht_b, wgu_t, inter,
      H_, (long)2048*2048, segStart, segCount, tileSeg, tileMb, meta, assignTS, assignW, nullptr);

  // MoE down: grouped B-dbuf pipeline, K=1024, grid (16 n, tiles)
  k_gemm_g<3><<<dim3(16,MAXTILE), 256, 0, stream>>>(inter, wd_t, nullptr,
      I_, (long)2048*1024, segStart, segCount, tileSeg, tileMb, meta, assignTS, assignW, downb);

  k_final<<<(T_*H_/4)/256, 256, 0, stream>>>(xa, downb, out);
}

// Round 18
// 793.125 us; speedup vs baseline: 1.1526x; 1.0432x over previous
//
#include <hip/hip_runtime.h>
#include <math.h>

typedef unsigned short u16;
typedef __attribute__((ext_vector_type(8))) short short8;
typedef __attribute__((ext_vector_type(4))) float f32x4;

#define B_ 2
#define S_ 1024
#define H_ 2048
#define DH_ 128
#define HQ_ 16
#define HKV_ 4
#define E_ 16
#define TOPK_ 4
#define I_ 1024
#define T_ (B_*S_)
#define NQKV_ 3072
#define NSEG_ 17
#define NA_ (T_*TOPK_ + T_)   /* 10240 assignments incl. shared */
#define K3_ 6144              /* logical 3*H for bf16x2 split GEMMs */
#define K2_ 4096              /* physical (hi,lo) row stride */
#define MAXTILE 97

#define QPLANE ((long)B_*HQ_*S_*DH_)   /* 4194304 */
#define KPLANE ((long)B_*HKV_*S_*DH_)  /* 1048576 */
#define VPLANE ((long)B_*HKV_*DH_*S_)  /* 1048576 */

// ---------------- numeric helpers ----------------
__device__ __forceinline__ float bf2f(u16 u){
  union { unsigned int i; float f; } x; x.i = ((unsigned int)u) << 16; return x.f;
}
__device__ __forceinline__ u16 f2bf(float f){
  union { float f; unsigned int i; } x; x.f = f;
  unsigned int r = x.i + 0x7fffu + ((x.i >> 16) & 1u);
  return (u16)(r >> 16);
}
__device__ __forceinline__ void split_bf(float v, u16& hi, u16& lo){
  hi = f2bf(v);
  lo = f2bf(v - bf2f(hi));
}

__device__ __forceinline__ void gld_lds16(const void* g, void* l){
  __builtin_amdgcn_global_load_lds(
      (const __attribute__((address_space(1))) unsigned int*)g,
      (__attribute__((address_space(3))) unsigned int*)l, 16, 0, 0);
}

__device__ __forceinline__ f32x4 mfma_bf16(short8 a, short8 b, f32x4 c){
  return __builtin_amdgcn_mfma_f32_16x16x32_bf16(a, b, c, 0, 0, 0);
}

// ---------------- fused preamble: all weight transposes + ropetab + bias copy + input rmsnorm ----------------
// Segment layout (blockIdx.x):
//   [0,8192)      wg   transpose (16x32 per expert x16), rowMul=2 rowOff=0
//   [8192,16384)  wu   transpose, rowMul=2 rowOff=1
//   [16384,24576) wd   transpose (32x16 per expert x16)
//   [24576,25600) wq   split transpose (32x32)
//   [25600,26624) wo   split transpose (32x32)
//   [26624,28672) rmsnorm(x) -> h2  (2048 blocks)
//   [28672,28928) wk   split transpose (8x32), rowOff=2048
//   [28928,29184) wv   split transpose (8x32), rowOff=2560
//   [29184,29696) swg  transpose (16x32), rowMul=2 rowOff=0
//   [29696,30208) swu  transpose, rowOff=1
//   [30208,30720) swd  transpose (32x16)
//   [30720,30976) ropetab (4 s per block)
//   [30976,30979) bias copies
__device__ __forceinline__ void do_transpose(const float* __restrict__ inp, u16* __restrict__ outp,
    int R, int C, int rowMul, int rowOff, int split3, int bx_i, int by_i,
    float (*tile)[65])
{
  int c0 = bx_i * 64, r0 = by_i * 64;
  int tid = threadIdx.x;
  int qc = (tid & 15) * 4;
  int rr = tid >> 4;
#pragma unroll
  for (int p = 0; p < 4; p++){
    int r = p*16 + rr;
    float4 v = *(const float4*)(inp + (long)(r0 + r)*C + c0 + qc);
    tile[r][qc] = v.x; tile[r][qc+1] = v.y; tile[r][qc+2] = v.z; tile[r][qc+3] = v.w;
  }
  __syncthreads();
  int rl = (tid & 15) * 4;
  int cw = tid >> 4;
#pragma unroll
  for (int p = 0; p < 4; p++){
    int c = p*16 + cw;
    float v0 = tile[rl][c], v1 = tile[rl+1][c], v2 = tile[rl+2][c], v3 = tile[rl+3][c];
    if (split3){
      ushort4 hi, lo;
      split_bf(v0, hi.x, lo.x); split_bf(v1, hi.y, lo.y);
      split_bf(v2, hi.z, lo.z); split_bf(v3, hi.w, lo.w);
      long base = (long)((c0 + c)*rowMul + rowOff) * (2*R) + r0 + rl;
      *(ushort4*)(outp + base)     = hi;
      *(ushort4*)(outp + base + R) = lo;
    } else {
      ushort4 hi = { f2bf(v0), f2bf(v1), f2bf(v2), f2bf(v3) };
      *(ushort4*)(outp + (long)((c0 + c)*rowMul + rowOff) * R + r0 + rl) = hi;
    }
  }
}

__global__ void k_pre(const float* __restrict__ x, const float* __restrict__ inlnw,
                      u16* __restrict__ h2,
                      const float* __restrict__ wq, const float* __restrict__ wk,
                      const float* __restrict__ wv, const float* __restrict__ wo,
                      const float* __restrict__ wg, const float* __restrict__ wu,
                      const float* __restrict__ wdp, const float* __restrict__ swg,
                      const float* __restrict__ swu, const float* __restrict__ swd,
                      const float* __restrict__ bq, const float* __restrict__ bk,
                      const float* __restrict__ bv,
                      u16* __restrict__ wqkv2, u16* __restrict__ wo2,
                      u16* __restrict__ wgu_t, u16* __restrict__ wd_t,
                      float* __restrict__ tab, float* __restrict__ biascat)
{
  __shared__ float tile[64][65];
  __shared__ float red[4];
  int bid = blockIdx.x;
  int tid = threadIdx.x;

  if (bid < 8192){                    // wg
    int z = bid >> 9, rem = bid & 511;
    do_transpose(wg + (long)z*2048*1024, wgu_t + (long)z*2048*2048,
                 2048, 1024, 2, 0, 0, rem & 15, rem >> 4, tile);
  } else if (bid < 16384){            // wu
    int loc = bid - 8192;
    int z = loc >> 9, rem = loc & 511;
    do_transpose(wu + (long)z*2048*1024, wgu_t + (long)z*2048*2048,
                 2048, 1024, 2, 1, 0, rem & 15, rem >> 4, tile);
  } else if (bid < 24576){            // wd
    int loc = bid - 16384;
    int z = loc >> 9, rem = loc & 511;
    do_transpose(wdp + (long)z*1024*2048, wd_t + (long)z*2048*1024,
                 1024, 2048, 1, 0, 0, rem & 31, rem >> 5, tile);
  } else if (bid < 25600){            // wq
    int loc = bid - 24576;
    do_transpose(wq, wqkv2, 2048, 2048, 1, 0, 1, loc & 31, loc >> 5, tile);
  } else if (bid < 26624){            // wo
    int loc = bid - 25600;
    do_transpose(wo, wo2, 2048, 2048, 1, 0, 1, loc & 31, loc >> 5, tile);
  } else if (bid < 28672){            // rmsnorm(x) -> h2
    int t = bid - 26624;
    const float4* r4 = (const float4*)(x + (long)t * H_);
    const float4* w4 = (const float4*)inlnw;
    float4 a = r4[tid], b = r4[tid + 256];
    float ss = a.x*a.x + a.y*a.y + a.z*a.z + a.w*a.w
             + b.x*b.x + b.y*b.y + b.z*b.z + b.w*b.w;
#pragma unroll
    for (int d = 1; d < 64; d <<= 1) ss += __shfl_xor(ss, d);
    int lane = tid & 63, wvid = tid >> 6;
    if (lane == 0) red[wvid] = ss;
    __syncthreads();
    ss = red[0] + red[1] + red[2] + red[3];
    float rs = rsqrtf(ss * (1.f / 2048.f) + 1e-5f);
    float4 wa = w4[tid], wb = w4[tid + 256];
    float va[8] = { a.x*rs*wa.x, a.y*rs*wa.y, a.z*rs*wa.z, a.w*rs*wa.w,
                    b.x*rs*wb.x, b.y*rs*wb.y, b.z*rs*wb.z, b.w*rs*wb.w };
    int pos0 = tid*4, pos1 = 1024 + tid*4;
    ushort4 hi0, lo0, hi1, lo1;
    split_bf(va[0], hi0.x, lo0.x); split_bf(va[1], hi0.y, lo0.y);
    split_bf(va[2], hi0.z, lo0.z); split_bf(va[3], hi0.w, lo0.w);
    split_bf(va[4], hi1.x, lo1.x); split_bf(va[5], hi1.y, lo1.y);
    split_bf(va[6], hi1.z, lo1.z); split_bf(va[7], hi1.w, lo1.w);
    u16* row = h2 + (long)t * K2_;
    *(ushort4*)(row + pos0) = hi0;        *(ushort4*)(row + pos1) = hi1;
    *(ushort4*)(row + 2048 + pos0) = lo0; *(ushort4*)(row + 2048 + pos1) = lo1;
  } else if (bid < 28928){            // wk
    int loc = bid - 28672;
    do_transpose(wk, wqkv2, 2048, 512, 1, 2048, 1, loc & 7, loc >> 3, tile);
  } else if (bid < 29184){            // wv
    int loc = bid - 28928;
    do_transpose(wv, wqkv2, 2048, 512, 1, 2560, 1, loc & 7, loc >> 3, tile);
  } else if (bid < 29696){            // swg
    int loc = bid - 29184;
    do_transpose(swg, wgu_t + (long)16*2048*2048, 2048, 1024, 2, 0, 0, loc & 15, loc >> 4, tile);
  } else if (bid < 30208){            // swu
    int loc = bid - 29696;
    do_transpose(swu, wgu_t + (long)16*2048*2048, 2048, 1024, 2, 1, 0, loc & 15, loc >> 4, tile);
  } else if (bid < 30720){            // swd
    int loc = bid - 30208;
    do_transpose(swd, wd_t + (long)16*2048*1024, 1024, 2048, 1, 0, 0, loc & 31, loc >> 5, tile);
  } else if (bid < 30976){            // ropetab (fp64)
    int loc = bid - 30720;
    int s = loc*4 + (tid >> 6);
    int i = tid & 63;
    double inv = pow(10000.0, -(double)i / 64.0);
    double fr = (double)s * inv;
    tab[s*128 + i]      = (float)cos(fr);
    tab[s*128 + 64 + i] = (float)sin(fr);
  } else {                            // bias copies
    int loc = bid - 30976;
    if (loc == 0){
#pragma unroll
      for (int p = 0; p < 2; p++){
        float4 v = *(const float4*)(bq + (tid*2 + p)*4);
        *(float4*)(biascat + (tid*2 + p)*4) = v;
      }
    } else if (loc == 1){
      if (tid < 128){
        float4 v = *(const float4*)(bk + tid*4);
        *(float4*)(biascat + 2048 + tid*4) = v;
      }
    } else {
      if (tid < 128){
        float4 v = *(const float4*)(bv + tid*4);
        *(float4*)(biascat + 2560 + tid*4) = v;
      }
    }
  }
}

// ---------------- WO + residual + RMSNorm fused ----------------
__global__ void k_add_rmsnorm(const float* __restrict__ x, const float* __restrict__ p0,
                              const float* __restrict__ w, float* __restrict__ xa,
                              u16* __restrict__ out1, float* __restrict__ outf)
{
  int t = blockIdx.x;
  long base = (long)t * H_;
  const float4* x4 = (const float4*)(x + base);
  const float4* a4 = (const float4*)(p0 + base);
  const float4* w4 = (const float4*)w;
  int i0 = threadIdx.x, i1 = threadIdx.x + 256;
  float4 xv0 = x4[i0], xv1 = x4[i1];
  float4 av0 = a4[i0], av1 = a4[i1];
  float4 s0, s1;
  s0.x = xv0.x+av0.x; s0.y = xv0.y+av0.y; s0.z = xv0.z+av0.z; s0.w = xv0.w+av0.w;
  s1.x = xv1.x+av1.x; s1.y = xv1.y+av1.y; s1.z = xv1.z+av1.z; s1.w = xv1.w+av1.w;
  *(float4*)(xa + base + i0*4) = s0;
  *(float4*)(xa + base + i1*4) = s1;
  float ss = s0.x*s0.x + s0.y*s0.y + s0.z*s0.z + s0.w*s0.w
           + s1.x*s1.x + s1.y*s1.y + s1.z*s1.z + s1.w*s1.w;
#pragma unroll
  for (int d = 1; d < 64; d <<= 1) ss += __shfl_xor(ss, d);
  __shared__ float red[4];
  int lane = threadIdx.x & 63, wv = threadIdx.x >> 6;
  if (lane == 0) red[wv] = ss;
  __syncthreads();
  ss = red[0] + red[1] + red[2] + red[3];
  float rs = rsqrtf(ss * (1.f / 2048.f) + 1e-5f);
  float4 wa = w4[i0], wb = w4[i1];
  float va[8] = { s0.x*rs*wa.x, s0.y*rs*wa.y, s0.z*rs*wa.z, s0.w*rs*wa.w,
                  s1.x*rs*wb.x, s1.y*rs*wb.y, s1.z*rs*wb.z, s1.w*rs*wb.w };
  ushort4 q0 = { f2bf(va[0]), f2bf(va[1]), f2bf(va[2]), f2bf(va[3]) };
  ushort4 q1 = { f2bf(va[4]), f2bf(va[5]), f2bf(va[6]), f2bf(va[7]) };
  *(ushort4*)(out1 + base + i0*4) = q0;
  *(ushort4*)(out1 + base + i1*4) = q1;
  float4 oa = { va[0], va[1], va[2], va[3] };
  float4 ob = { va[4], va[5], va[6], va[7] };
  *(float4*)(outf + base + i0*4) = oa;
  *(float4*)(outf + base + i1*4) = ob;
}

// ---------------- per-head QK norm + RoPE + hi/lo split layout ----------------
__global__ void k_ropenorm(const float* __restrict__ qkv, const float* __restrict__ biascat,
                           const float* __restrict__ qnw, const float* __restrict__ knw,
                           const float* __restrict__ tab,
                           u16* __restrict__ Q, u16* __restrict__ Kn, u16* __restrict__ Vt)
{
  long gw = (long)blockIdx.x * 4 + (threadIdx.x >> 6);
  int lane = threadIdx.x & 63;
  int hr = (int)(gw % 24);
  long bs = gw / 24;            // token index t = b*S + s
  int s = (int)(bs % S_);
  int b = (int)(bs / S_);
  long ro = bs * NQKV_ + hr * DH_;
  float x1 = qkv[ro + lane] + biascat[hr*DH_ + lane];
  float x2 = qkv[ro + lane + 64] + biascat[hr*DH_ + lane + 64];
  if (hr < 20){
    float ss = x1*x1 + x2*x2;
#pragma unroll
    for (int d = 1; d < 64; d <<= 1) ss += __shfl_xor(ss, d);
    float rs = rsqrtf(ss * (1.f/128.f) + 1e-5f);
    const float* wn = (hr < 16) ? qnw : knw;
    float y1 = x1 * rs * wn[lane], y2 = x2 * rs * wn[lane + 64];
    float c = tab[s*128 + lane], sn = tab[s*128 + 64 + lane];
    float o1 = y1*c - y2*sn, o2 = y2*c + y1*sn;
    if (hr < 16){
      const float sc = 0.088388347648318447f; // 1/sqrt(128)
      u16 h1,l1,h2,l2;
      split_bf(o1*sc, h1, l1); split_bf(o2*sc, h2, l2);
      u16* dst = Q + (((long)b*HQ_ + hr)*S_ + s) * DH_;
      dst[lane] = h1; dst[lane+64] = h2;
      dst[QPLANE + lane] = l1; dst[QPLANE + lane+64] = l2;
    } else {
      u16 h1,l1,h2,l2;
      split_bf(o1, h1, l1); split_bf(o2, h2, l2);
      u16* dst = Kn + (((long)b*HKV_ + (hr-16))*S_ + s) * DH_;
      dst[lane] = h1; dst[lane+64] = h2;
      dst[KPLANE + lane] = l1; dst[KPLANE + lane+64] = l2;
    }
  } else {
    u16 h1,l1,h2,l2;
    split_bf(x1, h1, l1); split_bf(x2, h2, l2);
    u16* dst = Vt + (((long)b*HKV_ + (hr-20))*DH_) * S_ + s;
    dst[(long)lane * S_]        = h1;
    dst[(long)(lane + 64) * S_] = h2;
    dst[VPLANE + (long)lane * S_]        = l1;
    dst[VPLANE + (long)(lane + 64) * S_] = l2;
  }
}

// ---------------- flash attention (causal, GQA 4:1), bf16x2 3-term MFMA ----------------
__launch_bounds__(256)
__global__ void k_attn(const u16* __restrict__ Q, const u16* __restrict__ Kn,
                       const u16* __restrict__ Vt, u16* __restrict__ O2)
{
  __shared__ u16 LDS[2*16384];
  int qb = (gridDim.x - 1) - blockIdx.x;   // longest blocks first (LPT)
  int h = blockIdx.y, b = blockIdx.z;
  int kvh = h >> 2;
  int q0 = qb * 64;
  int tid = threadIdx.x, lane = tid & 63, w = tid >> 6;

  const u16* Qg = Q  + (((long)b*HQ_  + h  )*S_ + q0) * DH_;
  const u16* Kg = Kn + (((long)b*HKV_ + kvh)*S_) * DH_;
  const u16* Vg = Vt + (((long)b*HKV_ + kvh)*DH_) * S_;

  short8 qh[4], ql[4];
  {
    long qrow = w*16 + (lane & 15);
    int coff = (lane >> 4) << 3;
#pragma unroll
    for (int kst = 0; kst < 4; kst++){
      qh[kst] = *(const short8*)(Qg + qrow*DH_ + kst*32 + coff);
      ql[kst] = *(const short8*)(Qg + QPLANE + qrow*DH_ + kst*32 + coff);
    }
  }

  long ksrc[2]; int kdst[2];
  long vsrc[2]; int vdst[2];
#pragma unroll
  for (int it = 0; it < 2; ++it){
    {
      int flat = it*256 + tid;
      int r = flat >> 4, pc = flat & 15;
      int c = pc ^ (((r&7) << 1) | ((r >> 3) & 1));
      ksrc[it] = (long)r*DH_ + c*8;
      kdst[it] = (it*256 + (w<<6))*8;
    }
    {
      int flat = it*256 + tid;
      int r = flat >> 2, pc = flat & 3;
      int c = pc ^ (r & 3);
      vsrc[it] = (long)r*S_ + c*8;
      vdst[it] = 8192 + (it*256 + (w<<6))*8;
    }
  }

  auto STAGE_K = [&](int jj){
    int bo = (jj & 1) * 16384;
    long joff = (long)jj*32*DH_;
#pragma unroll
    for (int it = 0; it < 2; ++it){
      gld_lds16(Kg + ksrc[it] + joff,          &LDS[bo + kdst[it]]);
      gld_lds16(Kg + KPLANE + ksrc[it] + joff, &LDS[bo + 4096 + kdst[it]]);
    }
  };
  auto STAGE_V = [&](int jj){
    int bo = (jj & 1) * 16384;
    long joff = (long)jj*32;
#pragma unroll
    for (int it = 0; it < 2; ++it){
      gld_lds16(Vg + vsrc[it] + joff,          &LDS[bo + vdst[it]]);
      gld_lds16(Vg + VPLANE + vsrc[it] + joff, &LDS[bo + 4096 + vdst[it]]);
    }
  };

  f32x4 o[8];
#pragma unroll
  for (int nt = 0; nt < 8; nt++) o[nt] = (f32x4){0.f,0.f,0.f,0.f};
  float mrow[4] = {-INFINITY,-INFINITY,-INFINITY,-INFINITY};
  float lrow[4] = {0.f,0.f,0.f,0.f};

  int jmax = 2*qb + 1;
  STAGE_K(0);
  STAGE_V(0);

  for (int j = 0; j <= jmax; ++j){
    if (j < jmax){
      STAGE_K(j+1);
      asm volatile("s_waitcnt vmcnt(8)" ::: "memory");
    } else {
      asm volatile("s_waitcnt vmcnt(4)" ::: "memory");
    }
    __builtin_amdgcn_s_barrier();
    __builtin_amdgcn_sched_barrier(0);

    const u16* Lb = &LDS[(j & 1) * 16384];
    u16* Pb = &LDS[((j + 1) & 1) * 16384 + 8192];

    f32x4 s[2];
#pragma unroll
    for (int nt = 0; nt < 2; nt++) s[nt] = (f32x4){0.f,0.f,0.f,0.f};
#pragma unroll
    for (int kst = 0; kst < 4; kst++){
#pragma unroll
      for (int nt = 0; nt < 2; nt++){
        int br = nt*16 + (lane & 15);
        int bc = (kst*4 + (lane >> 4)) ^ (((br&7)<<1) | ((br>>3)&1));
        short8 kh = *(const short8*)(Lb + br*128 + bc*8);
        short8 kl = *(const short8*)(Lb + 4096 + br*128 + bc*8);
        s[nt] = mfma_bf16(qh[kst], kh, s[nt]);
        s[nt] = mfma_bf16(qh[kst], kl, s[nt]);
        s[nt] = mfma_bf16(ql[kst], kh, s[nt]);
      }
    }
    if (j >= 2*qb){
#pragma unroll
      for (int nt = 0; nt < 2; nt++){
        int key = j*32 + nt*16 + (lane & 15);
#pragma unroll
        for (int r = 0; r < 4; r++){
          int qrow = q0 + w*16 + ((lane >> 4) << 2) + r;
          if (key > qrow) s[nt][r] = -1e30f;
        }
      }
    }
    float pm[4];
#pragma unroll
    for (int r = 0; r < 4; r++) pm[r] = fmaxf(s[0][r], s[1][r]);
#pragma unroll
    for (int d = 1; d < 16; d <<= 1){
#pragma unroll
      for (int r = 0; r < 4; r++) pm[r] = fmaxf(pm[r], __shfl_xor(pm[r], d));
    }
    float alpha[4];
#pragma unroll
    for (int r = 0; r < 4; r++){
      float mn = fmaxf(mrow[r], pm[r]);
      alpha[r] = __expf(mrow[r] - mn);
      mrow[r] = mn;
    }
    float psum[4] = {0.f,0.f,0.f,0.f};
#pragma unroll
    for (int nt = 0; nt < 2; nt++){
#pragma unroll
      for (int r = 0; r < 4; r++){
        float p = __expf(s[nt][r] - mrow[r]);
        psum[r] += p;
        u16 ph, pl; split_bf(p, ph, pl);
        int qr = ((lane>>4)<<2) + r, kc = nt*16 + (lane & 15);
        Pb[w*640 + qr*40 + kc]        = ph;
        Pb[2560 + w*640 + qr*40 + kc] = pl;
      }
    }
#pragma unroll
    for (int d = 1; d < 16; d <<= 1){
#pragma unroll
      for (int r = 0; r < 4; r++) psum[r] += __shfl_xor(psum[r], d);
    }
#pragma unroll
    for (int r = 0; r < 4; r++) lrow[r] = lrow[r]*alpha[r] + psum[r];
#pragma unroll
    for (int nt = 0; nt < 8; nt++)
#pragma unroll
      for (int r = 0; r < 4; r++) o[nt][r] *= alpha[r];

    if (j < jmax) asm volatile("s_waitcnt vmcnt(4)" ::: "memory");
    else          asm volatile("s_waitcnt vmcnt(0)" ::: "memory");
    __builtin_amdgcn_s_barrier();
    __builtin_amdgcn_sched_barrier(0);

    {
      short8 pah = *(const short8*)(Pb + w*640 + (lane & 15)*40 + ((lane >> 4) << 3));
      short8 pal = *(const short8*)(Pb + 2560 + w*640 + (lane & 15)*40 + ((lane >> 4) << 3));
#pragma unroll
      for (int nt = 0; nt < 8; nt++){
        int br = nt*16 + (lane & 15);
        int bc = (lane >> 4) ^ (br & 3);
        short8 vh = *(const short8*)(Lb + 8192 + br*32 + bc*8);
        short8 vl = *(const short8*)(Lb + 12288 + br*32 + bc*8);
        o[nt] = mfma_bf16(pah, vh, o[nt]);
        o[nt] = mfma_bf16(pah, vl, o[nt]);
        o[nt] = mfma_bf16(pal, vh, o[nt]);
      }
    }
    asm volatile("s_waitcnt lgkmcnt(0)" ::: "memory");
    __builtin_amdgcn_sched_barrier(0);
    __builtin_amdgcn_s_barrier();
    if (j < jmax) STAGE_V(j+1);
  }

  float inv_[4];
#pragma unroll
  for (int r = 0; r < 4; r++) inv_[r] = 1.f / lrow[r];
#pragma unroll
  for (int nt = 0; nt < 8; nt++){
#pragma unroll
    for (int r = 0; r < 4; r++){
      long row = (long)b*S_ + q0 + w*16 + ((lane >> 4) << 2) + r;
      float val = o[nt][r] * inv_[r];
      u16 hi, lo; split_bf(val, hi, lo);
      long base = row*K2_ + h*DH_ + nt*16 + (lane & 15);
      O2[base]        = hi;
      O2[base + 2048] = lo;
    }
  }
}

// ---------------- dense pipelined 128x128 GEMM (BK=32, 4-deep LDS, counted vmcnt) ----------------
template<int KITERS>
__launch_bounds__(256)
__global__ void k_gemm_d(const u16* __restrict__ A, const u16* __restrict__ Bm,
                         float* __restrict__ C, int N)
{
  __shared__ u16 LDS[4*8192];
  int tid = threadIdx.x;
  int lane = tid & 63, w = tid >> 6;
  int wr = w >> 1, wc = w & 1;
  int n0 = blockIdx.x * 128;
  int m0 = blockIdx.y * 128;

  const u16* aS[2]; const u16* bS[2];
#pragma unroll
  for (int it = 0; it < 2; ++it){
    int c = w + it*4;
    int row = c*16 + (lane >> 2);
    int ps = (lane & 3) ^ ((row >> 1) & 3);
    aS[it] = A + (long)(m0 + row) * K2_ + ps*8;
    bS[it] = Bm + (long)(n0 + row) * K2_ + ps*8;
  }

  int offA[4], offB[4];
#pragma unroll
  for (int m = 0; m < 4; m++){
    int r = wr*64 + m*16 + (lane & 15);
    int ps = (lane >> 4) ^ ((r >> 1) & 3);
    offA[m] = r*32 + ps*8;
  }
#pragma unroll
  for (int n = 0; n < 4; n++){
    int r = wc*64 + n*16 + (lane & 15);
    int ps = (lane >> 4) ^ ((r >> 1) & 3);
    offB[n] = 4096 + r*32 + ps*8;
  }

  f32x4 acc[4][4];
#pragma unroll
  for (int m = 0; m < 4; m++)
#pragma unroll
    for (int n = 0; n < 4; n++) acc[m][n] = (f32x4){0.f,0.f,0.f,0.f};

  auto STAGE = [&](int Tt){
    int kb = Tt * 32;
    int kA = (kb < 2048) ? kb : kb - 2048;
    int kB = (kb < 4096) ? kb : kb - 4096;
    int db = (Tt & 3) * 8192;
#pragma unroll
    for (int it = 0; it < 2; ++it){
      gld_lds16(aS[it] + kA, &LDS[db + (w + it*4)*512]);
      gld_lds16(bS[it] + kB, &LDS[db + 4096 + (w + it*4)*512]);
    }
  };

  STAGE(0); STAGE(1); STAGE(2);

  for (int T = 0; T < KITERS; ++T){
    if (T + 3 < KITERS) STAGE(T + 3);
    int rem = KITERS - 1 - T;
    if (rem >= 3)      asm volatile("s_waitcnt vmcnt(12)" ::: "memory");
    else if (rem == 2) asm volatile("s_waitcnt vmcnt(8)"  ::: "memory");
    else if (rem == 1) asm volatile("s_waitcnt vmcnt(4)"  ::: "memory");
    else               asm volatile("s_waitcnt vmcnt(0)"  ::: "memory");
    __builtin_amdgcn_s_barrier();
    __builtin_amdgcn_sched_barrier(0);
    const u16* L = &LDS[(T & 3) * 8192];
    short8 af[4], bfv[4];
#pragma unroll
    for (int m = 0; m < 4; m++) af[m]  = *(const short8*)(L + offA[m]);
#pragma unroll
    for (int n = 0; n < 4; n++) bfv[n] = *(const short8*)(L + offB[n]);
#pragma unroll
    for (int m = 0; m < 4; m++)
#pragma unroll
      for (int n = 0; n < 4; n++)
        acc[m][n] = mfma_bf16(af[m], bfv[n], acc[m][n]);
    asm volatile("s_waitcnt lgkmcnt(0)" ::: "memory");
    __builtin_amdgcn_sched_barrier(0);
    __builtin_amdgcn_s_barrier();
  }

#pragma unroll
  for (int m = 0; m < 4; m++){
    int row0 = m0 + wr*64 + m*16 + ((lane >> 4) << 2);
#pragma unroll
    for (int n = 0; n < 4; n++){
      int col = n0 + wc*64 + n*16 + (lane & 15);
#pragma unroll
      for (int r = 0; r < 4; r++)
        C[(long)(row0 + r)*N + col] = acc[m][n][r];
    }
  }
}

// ---------------- grouped 128x128 GEMM, BK=64, B-only double-buffer (48KB LDS) ----------------
// Grid (16 n-blocks, tiles) x-major — R14-proven: same-expert m-tiles sit 16 apart in
// flat id -> same XCD (16%8==0) -> private-L2 B reuse (measured FETCH 206MB vs 516MB swapped).
template<int MODE>
__launch_bounds__(256)
__global__ void k_gemm_g(const u16* __restrict__ A, const u16* __restrict__ Bm,
                         void* __restrict__ Cout,
                         int Kloop, long segStrideB,
                         const int* __restrict__ segStart, const int* __restrict__ segCount,
                         const int* __restrict__ tileSeg, const int* __restrict__ tileMb,
                         const int* __restrict__ meta,
                         const int* __restrict__ assignTS, const float* __restrict__ assignW,
                         u16* __restrict__ downb)
{
  __shared__ u16 LDS[3*8192];   // A: [0,8192), B0: [8192,16384), B1: [16384,24576)
  int tid = threadIdx.x;
  int lane = tid & 63, w = tid >> 6;
  int wr = w >> 1, wc = w & 1;
  int n0 = blockIdx.x * 128;
  int ty = blockIdx.y;
  if (ty >= meta[0]) return;
  int seg = tileSeg[ty], m0 = tileMb[ty] * 128;
  int segBase = segStart[seg];
  int cnt = segCount[seg];
  const u16* Bp = Bm + (long)seg * segStrideB;

  const u16* aS[4]; const u16* bS[4];
#pragma unroll
  for (int it = 0; it < 4; ++it){
    int flat = it*256 + tid;
    int r = flat >> 3, pc = flat & 7;
    int c = pc ^ (r & 7);
    long arow;
    if constexpr (MODE == 2) arow = (long)(assignTS[segBase + m0 + r] >> 3);
    else arow = (long)(segBase + m0 + r);
    aS[it] = A + arow * Kloop + c*8;
    bS[it] = Bp + (long)(n0 + r) * Kloop + c*8;
  }

  auto STAGE_A = [&](int Tt){
    int kb = Tt * 64;
#pragma unroll
    for (int it = 0; it < 4; ++it)
      gld_lds16(aS[it] + kb, &LDS[(it*256 + (w<<6))*8]);
  };
  auto STAGE_B = [&](int Tt){
    int kb = Tt * 64;
    int bb = 8192 + (Tt & 1)*8192;
#pragma unroll
    for (int it = 0; it < 4; ++it)
      gld_lds16(bS[it] + kb, &LDS[bb + (it*256 + (w<<6))*8]);
  };

  f32x4 acc[4][4];
#pragma unroll
  for (int m = 0; m < 4; m++)
#pragma unroll
    for (int n = 0; n < 4; n++) acc[m][n] = (f32x4){0.f,0.f,0.f,0.f};

  int NT = Kloop >> 6;
  STAGE_A(0); STAGE_B(0);

  for (int T = 0; T < NT; ++T){
    if (T + 1 < NT){
      STAGE_B(T + 1);
      asm volatile("s_waitcnt vmcnt(4)" ::: "memory");   // A(T)+B(T) landed; B(T+1) in flight
    } else {
      asm volatile("s_waitcnt vmcnt(0)" ::: "memory");
    }
    __builtin_amdgcn_s_barrier();
    __builtin_amdgcn_sched_barrier(0);
    const u16* Bb = &LDS[8192 + (T & 1)*8192];
#pragma unroll
    for (int kh = 0; kh < 2; ++kh){
      short8 af[4], bfv[4];
#pragma unroll
      for (int m = 0; m < 4; m++){
        int r = wr*64 + m*16 + (lane & 15);
        int c = (kh*4 + (lane >> 4)) ^ (r & 7);
        af[m] = *(const short8*)(&LDS[0] + r*64 + c*8);
      }
#pragma unroll
      for (int n = 0; n < 4; n++){
        int r = wc*64 + n*16 + (lane & 15);
        int c = (kh*4 + (lane >> 4)) ^ (r & 7);
        bfv[n] = *(const short8*)(Bb + r*64 + c*8);
      }
#pragma unroll
      for (int m = 0; m < 4; m++)
#pragma unroll
        for (int n = 0; n < 4; n++)
          acc[m][n] = mfma_bf16(af[m], bfv[n], acc[m][n]);
    }
    asm volatile("s_waitcnt lgkmcnt(0)" ::: "memory");
    __builtin_amdgcn_sched_barrier(0);
    __builtin_amdgcn_s_barrier();
    if (T + 1 < NT) STAGE_A(T + 1);   // A-buf readers done (lgkm drained + barrier)
  }

  if constexpr (MODE == 2){
    u16* inter = (u16*)Cout;
#pragma unroll
    for (int m = 0; m < 4; m++){
      int row0 = m0 + wr*64 + m*16 + ((lane >> 4) << 2);
#pragma unroll
      for (int n = 0; n < 4; n++){
        f32x4 a = acc[m][n];
        float ov[4];
#pragma unroll
        for (int r = 0; r < 4; r++) ov[r] = __shfl_xor(a[r], 1);
        if ((lane & 1) == 0){
          int colp = (n0 + wc*64 + n*16 + (lane & 15)) >> 1;
#pragma unroll
          for (int r = 0; r < 4; r++){
            int rl = row0 + r;
            if (rl < cnt){
              int pos = segBase + rl;
              float g = a[r], u = ov[r];
              float val = (g / (1.f + __expf(-g))) * u * assignW[pos];
              inter[(long)pos*I_ + colp] = f2bf(val);
            }
          }
        }
      }
    }
  } else {
#pragma unroll
    for (int m = 0; m < 4; m++){
      int row0 = m0 + wr*64 + m*16 + ((lane >> 4) << 2);
#pragma unroll
      for (int n = 0; n < 4; n++){
        int col = n0 + wc*64 + n*16 + (lane & 15);
#pragma unroll
        for (int r = 0; r < 4; r++){
          int rl = row0 + r;
          if (rl < cnt){
            int ts = assignTS[segBase + rl];
            downb[((long)(ts >> 3)*5 + (ts & 7))*H_ + col] = f2bf(acc[m][n][r]);
          }
        }
      }
    }
  }
}

// ---------------- router (fp32, wave-per-token, streamed row / all-expert acc) ----------------
__global__ void k_router(const float* __restrict__ ht, const float* __restrict__ gw,
                         const float* __restrict__ gb, int* __restrict__ tok_e,
                         float* __restrict__ tok_w, int* __restrict__ counts)
{
  int t = blockIdx.x * 4 + (threadIdx.x >> 6);
  int lane = threadIdx.x & 63;
  const float4* row4 = (const float4*)(ht + (long)t * H_);
  float acc[16];
#pragma unroll
  for (int e = 0; e < 16; e++) acc[e] = 0.f;
#pragma unroll
  for (int it = 0; it < 8; it++){
    float4 rv = row4[lane + 64*it];
#pragma unroll
    for (int e = 0; e < 16; e++){
      float4 gv = *(const float4*)(gw + (long)e*H_ + (lane + 64*it)*4);
      acc[e] += rv.x*gv.x + rv.y*gv.y + rv.z*gv.z + rv.w*gv.w;
    }
  }
#pragma unroll
  for (int d = 1; d < 64; d <<= 1){
#pragma unroll
    for (int e = 0; e < 16; e++) acc[e] += __shfl_xor(acc[e], d);
  }
  if (lane == 0){
    float scr[16], ch[16];
#pragma unroll
    for (int e = 0; e < 16; e++){
      float s = 1.f / (1.f + __expf(-acc[e]));
      scr[e] = s; ch[e] = s + gb[e];
    }
    int sel[4]; float tw[4]; float sum = 0.f;
#pragma unroll
    for (int k = 0; k < 4; k++){
      int best = -1; float bv = -1e30f;
      for (int e = 0; e < 16; e++){
        bool used = false;
        for (int j = 0; j < k; j++) if (sel[j] == e) used = true;
        if (!used && ch[e] > bv){ bv = ch[e]; best = e; }
      }
      sel[k] = best; tw[k] = scr[best]; sum += scr[best];
    }
    float inv = 1.f / (sum + 1e-20f);
#pragma unroll
    for (int k = 0; k < 4; k++){
      tok_e[t*4 + k] = sel[k];
      tok_w[t*4 + k] = tw[k] * inv;
      atomicAdd(&counts[sel[k]], 1);
    }
  }
}

__global__ void k_scan(const int* __restrict__ counts, int* __restrict__ segStart,
                       int* __restrict__ segCount, int* __restrict__ cursor,
                       int* __restrict__ tileSeg, int* __restrict__ tileMb,
                       int* __restrict__ meta)
{
  if (threadIdx.x == 0){
    int off = 0, nt = 0;
    for (int e = 0; e < 16; e++){
      segStart[e] = off; segCount[e] = counts[e]; cursor[e] = off;
      for (int mb = 0; mb*128 < counts[e]; ++mb){ tileSeg[nt] = e; tileMb[nt] = mb; nt++; }
      off += counts[e];
    }
    segStart[16] = T_*TOPK_; segCount[16] = T_;
    for (int mb = 0; mb < 16; ++mb){ tileSeg[nt] = 16; tileMb[nt] = mb; nt++; }
    meta[0] = nt;
  }
}

__global__ void k_scatter(const int* __restrict__ tok_e, const float* __restrict__ tok_w,
                          int* __restrict__ cursor, int* __restrict__ assignTS,
                          float* __restrict__ assignW)
{
  int t = blockIdx.x*256 + threadIdx.x;
  if (t < T_){
    for (int k = 0; k < 4; k++){
      int e = tok_e[t*4 + k];
      int pos = atomicAdd(&cursor[e], 1);
      assignTS[pos] = t*8 + k;
      assignW[pos] = tok_w[t*4 + k];
    }
    assignTS[T_*TOPK_ + t] = t*8 + 4;
    assignW[T_*TOPK_ + t] = 1.f;
  }
}

// ---------------- final: out = xa + sum_slots down ----------------
__global__ void k_final(const float* __restrict__ xa, const u16* __restrict__ downb,
                        float* __restrict__ out)
{
  long i = ((long)blockIdx.x*256 + threadIdx.x) * 4;
  int t = (int)(i >> 11);
  int h = (int)(i & 2047);
  float4 r = *(const float4*)(xa + i);
  float a0 = r.x, a1 = r.y, a2 = r.z, a3 = r.w;
#pragma unroll
  for (int k = 0; k < 5; k++){
    const u16* d = downb + ((long)t*5 + k)*H_ + h;
    ushort4 v = *(const ushort4*)d;
    a0 += bf2f(v.x); a1 += bf2f(v.y); a2 += bf2f(v.z); a3 += bf2f(v.w);
  }
  float4 o = { a0, a1, a2, a3 };
  *(float4*)(out + i) = o;
}

// ---------------- host ----------------
extern "C" void kernel_launch(void* const* d_in, const int* in_sizes, int n_in,
                              void* d_out, int out_size, void* d_ws, size_t ws_size,
                              hipStream_t stream)
{
  (void)in_sizes; (void)n_in; (void)out_size; (void)ws_size;
  const float* x      = (const float*)d_in[0];
  const float* inlnw  = (const float*)d_in[1];
  const float* wq     = (const float*)d_in[2];
  const float* bq     = (const float*)d_in[3];
  const float* wk     = (const float*)d_in[4];
  const float* bk     = (const float*)d_in[5];
  const float* wv     = (const float*)d_in[6];
  const float* bv     = (const float*)d_in[7];
  const float* qnw    = (const float*)d_in[8];
  const float* knw    = (const float*)d_in[9];
  const float* wo     = (const float*)d_in[10];
  const float* postln = (const float*)d_in[11];
  const float* gatew  = (const float*)d_in[12];
  const float* gateb  = (const float*)d_in[13];
  const float* wg     = (const float*)d_in[14];
  const float* wu     = (const float*)d_in[15];
  const float* wdp    = (const float*)d_in[16];
  const float* swg    = (const float*)d_in[17];
  const float* swu    = (const float*)d_in[18];
  const float* swd    = (const float*)d_in[19];
  float* out = (float*)d_out;

  char* ws = (char*)d_ws;
  size_t off = 0;
  auto alloc = [&](size_t bytes) -> char* {
    char* p = ws + off; off += (bytes + 255) & ~(size_t)255; return p;
  };
  // persistent
  u16*   wqkv2   = (u16*)  alloc((size_t)NQKV_*K2_*2);     // 25.17 MB (hi,lo)
  u16*   wo2     = (u16*)  alloc((size_t)H_*K2_*2);        // 16.78 MB (hi,lo)
  u16*   wgu_t   = (u16*)  alloc((size_t)NSEG_*2048*2048*2); // 142.6 MB
  u16*   wd_t    = (u16*)  alloc((size_t)NSEG_*2048*1024*2); // 71.3 MB
  float* tab     = (float*)alloc((size_t)S_*128*4);
  float* biascat = (float*)alloc((size_t)NQKV_*4);
  float* xa      = (float*)alloc((size_t)T_*H_*4);         // 16.78 MB
  int*   tok_e   = (int*)  alloc((size_t)T_*4*4);
  float* tok_w   = (float*)alloc((size_t)T_*4*4);
  int*   counts  = (int*)  alloc(32*4);
  int*   segStart= (int*)  alloc(32*4);
  int*   segCount= (int*)  alloc(32*4);
  int*   cursor  = (int*)  alloc(32*4);
  int*   tileSeg = (int*)  alloc(128*4);
  int*   tileMb  = (int*)  alloc(128*4);
  int*   meta    = (int*)  alloc(32*4);
  int*   assignTS= (int*)  alloc((size_t)NA_*4);
  float* assignW = (float*)alloc((size_t)NA_*4);
  // scratch regions (re-used across phases)
  char*  scrA    = alloc((size_t)NA_*I_*2);                // 20.97 MB: h2 -> attno2 -> inter
  char*  scrBC   = alloc((size_t)2*T_*NQKV_*4);            // 50.33 MB: qkv -> wop
  char*  scrD    = alloc((size_t)(2*QPLANE + 2*KPLANE + 2*VPLANE)*2); // 25.17 MB: Q/K/V -> ht -> downb

  u16*   h2      = (u16*)scrA;
  u16*   attno2  = (u16*)scrA;
  u16*   inter   = (u16*)scrA;
  float* qkvp0   = (float*)scrBC;
  float* wop     = (float*)scrBC;
  u16*   Qb2     = (u16*)scrD;
  u16*   Kn2     = (u16*)(scrD + (size_t)2*QPLANE*2);
  u16*   Vt2     = (u16*)(scrD + (size_t)2*QPLANE*2 + (size_t)2*KPLANE*2);
  float* ht_f    = (float*)scrD;
  u16*   ht_b    = (u16*)(scrD + (size_t)T_*H_*4);
  u16*   downb   = (u16*)scrD;

  // fused preamble: all weight transposes + ropetab + bias copies + input rmsnorm (1 dispatch)
  k_pre<<<30979, 256, 0, stream>>>(x, inlnw, h2, wq, wk, wv, wo, wg, wu, wdp,
      swg, swu, swd, bq, bk, bv, wqkv2, wo2, wgu_t, wd_t, tab, biascat);

  // QKV: logical K=6144 (192 BK32 iters) over (hi,lo) storage
  k_gemm_d<192><<<dim3(24,16), 256, 0, stream>>>(h2, wqkv2, qkvp0, NQKV_);

  k_ropenorm<<<(T_*24)/4, 256, 0, stream>>>(qkvp0, biascat, qnw, knw, tab, Qb2, Kn2, Vt2);

  k_attn<<<dim3(S_/64, HQ_, B_), 256, 0, stream>>>(Qb2, Kn2, Vt2, attno2);

  // WO: logical K=6144 over (hi,lo) storage
  k_gemm_d<192><<<dim3(16,16), 256, 0, stream>>>(attno2, wo2, wop, H_);

  // xa = x + wop; ht = rmsnorm(xa)*postln
  k_add_rmsnorm<<<T_, 256, 0, stream>>>(x, wop, postln, xa, ht_b, ht_f);

  hipMemsetAsync(counts, 0, 32*4, stream);
  k_router<<<T_/4, 256, 0, stream>>>(ht_f, gatew, gateb, tok_e, tok_w, counts);
  k_scan<<<1, 64, 0, stream>>>(counts, segStart, segCount, cursor, tileSeg, tileMb, meta);
  k_scatter<<<(T_+255)/256, 256, 0, stream>>>(tok_e, tok_w, cursor, assignTS, assignW);

  // MoE gate/up: grouped B-dbuf pipeline, K=2048, grid (16 n, tiles) — R14-proven layout
  k_gemm_g<2><<<dim3(16,MAXTILE), 256, 0, stream>>>(ht_b, wgu_t, inter,
      H_, (long)2048*2048, segStart, segCount, tileSeg, tileMb, meta, assignTS, assignW, nullptr);

  // MoE down: grouped B-dbuf pipeline, K=1024, grid (16 n, tiles)
  k_gemm_g<3><<<dim3(16,MAXTILE), 256, 0, stream>>>(inter, wd_t, nullptr,
      I_, (long)2048*1024, segStart, segCount, tileSeg, tileMb, meta, assignTS, assignW, downb);

  k_final<<<(T_*H_/4)/256, 256, 0, stream>>>(xa, downb, out);
}